// Round 26
// baseline (142.938 us; speedup 1.0000x reference)
//
#include <hip/hip_runtime.h>
#include <hip/hip_bf16.h>
#include <cstddef>

static constexpr int BATCH = 16;
static constexpr int NCOPY = 16;
static constexpr int SSTR  = NCOPY * 512;   // floats per stat set

typedef __attribute__((ext_vector_type(8))) short bf16x8;
typedef __attribute__((ext_vector_type(4))) float f32x4;

__device__ __forceinline__ unsigned short f2bf(float f) {
  unsigned u = __float_as_uint(f);
  return (unsigned short)((u + 0x7fffu + ((u >> 16) & 1u)) >> 16);  // RNE
}

// pack two f32 -> bf16x2 in one v_perm_b32 (round-half-up via +0x8000)
__device__ __forceinline__ unsigned pack_bf2(float lo, float hi) {
  return __builtin_amdgcn_perm(__float_as_uint(hi) + 0x8000u,
                               __float_as_uint(lo) + 0x8000u,
                               0x07060302u);
}

#define SEL4(dst, arr, idx)                                   \
  do {                                                        \
    if ((idx) == 0) dst = arr[0];                             \
    else if ((idx) == 1) dst = arr[1];                        \
    else if ((idx) == 2) dst = arr[2];                        \
    else dst = arr[3];                                        \
  } while (0)

// ---- fused prep: [0,256) wcvt 16 mats; [256,641) init zero; [641,1153) xcvt
struct WcvtArgs { const float* p[16]; int sz[16]; int off[16]; };
__global__ __launch_bounds__(256)
void prep_kernel(WcvtArgs a, unsigned short* __restrict__ wdst,
                 float* __restrict__ initp, int initN,
                 const float* __restrict__ XA, const float* __restrict__ XB,
                 unsigned short* __restrict__ XAt, unsigned short* __restrict__ XBt) {
  __shared__ float ts[64][66];
  const int bx = blockIdx.x;
  const int tid = threadIdx.x;
  if (bx < 256) {
    const int t = bx >> 4, sub = bx & 15;
    const float* src = a.p[t];
    unsigned short* d = wdst + a.off[t];
    const int sz = a.sz[t];
    for (int i = sub * 256 + tid; i < sz; i += 4096)
      d[i] = f2bf(src[i]);
  } else if (bx < 641) {
    int idx = (bx - 256) * 256 + tid;
    if (idx < initN) initp[idx] = 0.f;
  } else {
    const int bx2 = bx - 641;
    const int z = bx2 >> 8;
    const int rem = bx2 & 255;
    const int b = rem >> 4;
    const int n0 = (rem & 15) << 6;
    const float* X = z ? XB : XA;
    unsigned short* XT = z ? XBt : XAt;
#pragma unroll
    for (int it = 0; it < 4; ++it) {
      int idx = it * 256 + tid;
      int c = idx >> 4, nq = (idx & 15) << 2;
      float4 v = *reinterpret_cast<const float4*>(X + ((size_t)(b * 64 + c) << 10) + n0 + nq);
      ts[c][nq] = v.x; ts[c][nq + 1] = v.y; ts[c][nq + 2] = v.z; ts[c][nq + 3] = v.w;
    }
    __syncthreads();
    const int n = tid >> 2, c0 = (tid & 3) << 4;
    unsigned short* dst = XT + ((size_t)(b * 1024 + n0 + n) << 6) + c0;
    unsigned w0 = (unsigned)f2bf(ts[c0 + 0][n]) | ((unsigned)f2bf(ts[c0 + 1][n]) << 16);
    unsigned w1 = (unsigned)f2bf(ts[c0 + 2][n]) | ((unsigned)f2bf(ts[c0 + 3][n]) << 16);
    unsigned w2 = (unsigned)f2bf(ts[c0 + 4][n]) | ((unsigned)f2bf(ts[c0 + 5][n]) << 16);
    unsigned w3 = (unsigned)f2bf(ts[c0 + 6][n]) | ((unsigned)f2bf(ts[c0 + 7][n]) << 16);
    unsigned w4 = (unsigned)f2bf(ts[c0 + 8][n]) | ((unsigned)f2bf(ts[c0 + 9][n]) << 16);
    unsigned w5 = (unsigned)f2bf(ts[c0 + 10][n]) | ((unsigned)f2bf(ts[c0 + 11][n]) << 16);
    unsigned w6 = (unsigned)f2bf(ts[c0 + 12][n]) | ((unsigned)f2bf(ts[c0 + 13][n]) << 16);
    unsigned w7 = (unsigned)f2bf(ts[c0 + 14][n]) | ((unsigned)f2bf(ts[c0 + 15][n]) << 16);
    *reinterpret_cast<uint4*>(dst) = make_uint4(w0, w1, w2, w3);
    *reinterpret_cast<uint4*>(dst + 8) = make_uint4(w4, w5, w6, w7);
  }
}

// ---- qk via MFMA: 4 projections; Q -> [b][n][64], K -> [b][c][n] -----------
struct QBias { const float* p[4]; };
__global__ __launch_bounds__(256, 4)
void qk_mfma_kernel(const unsigned short* __restrict__ XAt,
                    const unsigned short* __restrict__ XBt,
                    const unsigned short* __restrict__ wq,
                    QBias qb,
                    unsigned short* __restrict__ QAt, unsigned short* __restrict__ QBt,
                    unsigned short* __restrict__ KAc, unsigned short* __restrict__ KBc) {
  __shared__ __align__(16) unsigned char Xs[64 * 128];
  const int tid = threadIdx.x;
  const int lane = tid & 63, w = tid >> 6;
  const int g = lane >> 4, m = lane & 15;
  const int nbase = blockIdx.x << 6;
  const int z = blockIdx.y;
  const int which = z >> 4;
  const int b = z & 15;
  const unsigned short* XT = (which & 1) ? XBt : XAt;
  const unsigned short* Wb = wq + which * 4096;
  const float* bias;
  SEL4(bias, qb.p, which);
#pragma unroll
  for (int it = 0; it < 2; ++it) {
    int idx = it * 256 + tid;
    int row = idx >> 3, cc = idx & 7;
    bf16x8 v = *reinterpret_cast<const bf16x8*>(
        XT + ((size_t)(b * 1024 + nbase + row) << 6) + cc * 8);
    const int byte = (cc << 4) ^ ((row & 7) << 4);
    *reinterpret_cast<bf16x8*>(Xs + row * 128 + byte) = v;
  }
  __syncthreads();
  const int o0 = w << 4;
  const unsigned short* Wr = Wb + (size_t)(o0 + m) * 64 + (g << 3);
  bf16x8 af0 = *reinterpret_cast<const bf16x8*>(Wr);
  bf16x8 af1 = *reinterpret_cast<const bf16x8*>(Wr + 32);
  float bv[4];
#pragma unroll
  for (int r = 0; r < 4; ++r) bv[r] = bias[o0 + (g << 2) + r];
#pragma unroll
  for (int nt = 0; nt < 4; ++nt) {
    const int row = (nt << 4) + m;
    const unsigned char* lrow = Xs + row * 128;
    const int swz = (row & 7) << 4;
    f32x4 acc = (f32x4){0.f, 0.f, 0.f, 0.f};
    {
      bf16x8 b0 = *reinterpret_cast<const bf16x8*>(lrow + ((g << 4) ^ swz));
      acc = __builtin_amdgcn_mfma_f32_16x16x32_bf16(af0, b0, acc, 0, 0, 0);
      bf16x8 b1 = *reinterpret_cast<const bf16x8*>(lrow + ((64 + (g << 4)) ^ swz));
      acc = __builtin_amdgcn_mfma_f32_16x16x32_bf16(af1, b1, acc, 0, 0, 0);
    }
#pragma unroll
    for (int r = 0; r < 4; ++r) acc[r] += bv[r];
    if (which < 2) {
      unsigned short* Yq = (which == 0) ? QAt : QBt;
      ushort4 v;
      v.x = f2bf(acc[0]); v.y = f2bf(acc[1]);
      v.z = f2bf(acc[2]); v.w = f2bf(acc[3]);
      *reinterpret_cast<ushort4*>(
          Yq + ((size_t)(b * 1024 + nbase + row) << 6) + o0 + (g << 2)) = v;
    } else {
      unsigned short* Kc = (which == 2) ? KAc : KBc;
#pragma unroll
      for (int r = 0; r < 4; ++r)
        Kc[((size_t)b << 16) + ((size_t)(o0 + (g << 2) + r) << 10) + nbase + row] =
            f2bf(acc[r]);
    }
  }
}

// ---- combined MFMA attention: z<16 -> PV (batch z), z>=16 -> PtV (z-16) ----
// Q operands live in registers / direct global loads; only P round-trips LDS.
__global__ __launch_bounds__(256)
void attn_mfma_kernel(const unsigned short* __restrict__ QAt,
                      const unsigned short* __restrict__ QBt,
                      const unsigned short* __restrict__ KAc,
                      const unsigned short* __restrict__ KBc,
                      float* __restrict__ PART, float* __restrict__ bsum) {
  __shared__ __align__(16) unsigned short Pl[4096];
  __shared__ float red[256];
  const int tid = threadIdx.x;
  const int lane = tid & 63, w = tid >> 6;
  const int g = lane >> 4, m = lane & 15;
  const int z = blockIdx.z;
  const bool isPV = (z < 16);
  const int b = z & 15;
  const size_t nb = (size_t)b << 16;
  const size_t M1 = (size_t)1 << 20;

  if (isPV) {
    const int i0 = blockIdx.x << 6;
    const int jbase = blockIdx.y << 9;
    // fixed QA tile fragments in registers (B operand rows irow=(n<<4)|m)
    bf16x8 ua0[4], ua1[4];
#pragma unroll
    for (int n = 0; n < 4; ++n) {
      const int irow = (n << 4) | m;
      const unsigned short* p = QAt + nb + ((size_t)(i0 + irow) << 6) + (g << 3);
      ua0[n] = *reinterpret_cast<const bf16x8*>(p);
      ua1[n] = *reinterpret_cast<const bf16x8*>(p + 32);
    }
    f32x4 accO[4];
#pragma unroll
    for (int n = 0; n < 4; ++n) accO[n] = (f32x4){0.f, 0.f, 0.f, 0.f};
    float psum = 0.f;
    for (int jt = 0; jt < 8; ++jt) {
      const int j0 = jbase + (jt << 6);
      // A operand: QB row jrow, direct from global (coalesced 16B/lane)
      const int jrow = (w << 4) | m;
      const unsigned short* qbp = QBt + nb + ((size_t)(j0 + jrow) << 6) + (g << 3);
      bf16x8 a0 = *reinterpret_cast<const bf16x8*>(qbp);
      bf16x8 a1 = *reinterpret_cast<const bf16x8*>(qbp + 32);
      const int crow = (w << 4) | m;
      const unsigned short* kbp = KBc + nb + ((size_t)crow << 10) + j0 + (g << 3);
      bf16x8 ka0 = *reinterpret_cast<const bf16x8*>(kbp);
      bf16x8 ka1 = *reinterpret_cast<const bf16x8*>(kbp + 32);
      f32x4 e[4];
#pragma unroll
      for (int n = 0; n < 4; ++n) {
        e[n] = (f32x4){0.f, 0.f, 0.f, 0.f};
        e[n] = __builtin_amdgcn_mfma_f32_16x16x32_bf16(a0, ua0[n], e[n], 0, 0, 0);
        e[n] = __builtin_amdgcn_mfma_f32_16x16x32_bf16(a1, ua1[n], e[n], 0, 0, 0);
      }
      __syncthreads();  // previous iteration's P reads complete
      const int j = (w << 4) | (g << 2);
#pragma unroll
      for (int n = 0; n < 4; ++n) {
        const int irow = (n << 4) | m;
        float p0 = __expf(-e[n][0]), p1 = __expf(-e[n][1]);
        float p2 = __expf(-e[n][2]), p3 = __expf(-e[n][3]);
        psum += (p0 + p1) + (p2 + p3);
        unsigned pk01 = pack_bf2(p0, p1);
        unsigned pk23 = pack_bf2(p2, p3);
        int base = irow << 6;
        int off0 = base + ((((j) >> 3) ^ (irow & 7)) << 3) + (j & 7);
        int off2 = base + ((((j + 2) >> 3) ^ (irow & 7)) << 3) + ((j + 2) & 7);
        *reinterpret_cast<unsigned*>(Pl + off0) = pk01;
        *reinterpret_cast<unsigned*>(Pl + off2) = pk23;
      }
      __syncthreads();  // P writes visible
#pragma unroll
      for (int n = 0; n < 4; ++n) {
        const int irow = (n << 4) | m;
        bf16x8 p0 = *reinterpret_cast<const bf16x8*>(Pl + (irow << 6) + ((g ^ (irow & 7)) << 3));
        bf16x8 p1 = *reinterpret_cast<const bf16x8*>(Pl + (irow << 6) + (((g + 4) ^ (irow & 7)) << 3));
        accO[n] = __builtin_amdgcn_mfma_f32_16x16x32_bf16(ka0, p0, accO[n], 0, 0, 0);
        accO[n] = __builtin_amdgcn_mfma_f32_16x16x32_bf16(ka1, p1, accO[n], 0, 0, 0);
      }
    }
    float* OUT = PART + ((size_t)blockIdx.y * M1) + nb;
#pragma unroll
    for (int n = 0; n < 4; ++n) {
      const int ig = i0 + (n << 4) + m;
      const int c = (w << 4) + (g << 2);
      float4 o;
      o.x = accO[n][0]; o.y = accO[n][1]; o.z = accO[n][2]; o.w = accO[n][3];
      *reinterpret_cast<float4*>(OUT + ((size_t)ig << 6) + c) = o;
    }
    red[tid] = psum; __syncthreads();
    for (int s = 128; s > 0; s >>= 1) {
      if (tid < s) red[tid] += red[tid + s];
      __syncthreads();
    }
    if (tid == 0) atomicAdd(bsum + b, red[0]);
  } else {
    const int j0 = blockIdx.x << 6;
    const int ibase = blockIdx.y << 9;
    // fixed QB tile fragments in registers (B operand rows jrow=(n<<4)|m)
    bf16x8 ub0[4], ub1[4];
#pragma unroll
    for (int n = 0; n < 4; ++n) {
      const int jrow = (n << 4) | m;
      const unsigned short* p = QBt + nb + ((size_t)(j0 + jrow) << 6) + (g << 3);
      ub0[n] = *reinterpret_cast<const bf16x8*>(p);
      ub1[n] = *reinterpret_cast<const bf16x8*>(p + 32);
    }
    f32x4 accO[4];
#pragma unroll
    for (int n = 0; n < 4; ++n) accO[n] = (f32x4){0.f, 0.f, 0.f, 0.f};
    for (int it = 0; it < 8; ++it) {
      const int i0 = ibase + (it << 6);
      const int irow_a = (w << 4) | m;
      const unsigned short* qap = QAt + nb + ((size_t)(i0 + irow_a) << 6) + (g << 3);
      bf16x8 a0 = *reinterpret_cast<const bf16x8*>(qap);
      bf16x8 a1 = *reinterpret_cast<const bf16x8*>(qap + 32);
      const int crow = (w << 4) | m;
      const unsigned short* kap = KAc + nb + ((size_t)crow << 10) + i0 + (g << 3);
      bf16x8 ka0 = *reinterpret_cast<const bf16x8*>(kap);
      bf16x8 ka1 = *reinterpret_cast<const bf16x8*>(kap + 32);
      f32x4 e[4];
#pragma unroll
      for (int n = 0; n < 4; ++n) {
        e[n] = (f32x4){0.f, 0.f, 0.f, 0.f};
        e[n] = __builtin_amdgcn_mfma_f32_16x16x32_bf16(a0, ub0[n], e[n], 0, 0, 0);
        e[n] = __builtin_amdgcn_mfma_f32_16x16x32_bf16(a1, ub1[n], e[n], 0, 0, 0);
      }
      __syncthreads();
      const int i = (w << 4) | (g << 2);
#pragma unroll
      for (int n = 0; n < 4; ++n) {
        const int jrow = (n << 4) | m;
        float p0 = __expf(-e[n][0]), p1 = __expf(-e[n][1]);
        float p2 = __expf(-e[n][2]), p3 = __expf(-e[n][3]);
        unsigned pk01 = pack_bf2(p0, p1);
        unsigned pk23 = pack_bf2(p2, p3);
        int base = jrow << 6;
        int off0 = base + ((((i) >> 3) ^ (jrow & 7)) << 3) + (i & 7);
        int off2 = base + ((((i + 2) >> 3) ^ (jrow & 7)) << 3) + ((i + 2) & 7);
        *reinterpret_cast<unsigned*>(Pl + off0) = pk01;
        *reinterpret_cast<unsigned*>(Pl + off2) = pk23;
      }
      __syncthreads();
#pragma unroll
      for (int n = 0; n < 4; ++n) {
        const int jrow = (n << 4) | m;
        bf16x8 p0 = *reinterpret_cast<const bf16x8*>(Pl + (jrow << 6) + ((g ^ (jrow & 7)) << 3));
        bf16x8 p1 = *reinterpret_cast<const bf16x8*>(Pl + (jrow << 6) + (((g + 4) ^ (jrow & 7)) << 3));
        accO[n] = __builtin_amdgcn_mfma_f32_16x16x32_bf16(ka0, p0, accO[n], 0, 0, 0);
        accO[n] = __builtin_amdgcn_mfma_f32_16x16x32_bf16(ka1, p1, accO[n], 0, 0, 0);
      }
    }
    float* OUT = PART + 2 * M1 + ((size_t)blockIdx.y * M1) + nb;
#pragma unroll
    for (int n = 0; n < 4; ++n) {
      const int jg = j0 + (n << 4) + m;
      const int c = (w << 4) + (g << 2);
      float4 o;
      o.x = accO[n][0]; o.y = accO[n][1]; o.z = accO[n][2]; o.w = accO[n][3];
      *reinterpret_cast<float4*>(OUT + ((size_t)jg << 6) + c) = o;
    }
  }
}

// ---- gamma/beta pointer sets (per z, uniform SEL4) -------------------------
struct GBArgs { const float* g0[4]; const float* b0[4];
                const float* g1[4]; const float* b1[4]; };

// ---- MFMA conv v13: LDS-staged tile, OC output groups per wave -------------
// SMODE: 0 plain; 1 relu(bn0(T)); 2 relu(bn0(T)+S); 3 relu(bn0(T)+bn1(S));
//        4 concat(XAt low, (PART0+PART1)/bsum high) + Y0 global store
template<int CIN, int OC, int SMODE, int XDIV>
__global__ __launch_bounds__(256, 4)
void conv_mfma_kernel(const unsigned short* __restrict__ T0,
                      const unsigned short* __restrict__ S0,
                      const unsigned short* __restrict__ W0,
                      unsigned short* __restrict__ Yout0,
                      const float* __restrict__ sums0A, long s0str,
                      const float* __restrict__ sums1A, long s1str,
                      GBArgs gb,
                      float* __restrict__ outSums0,
                      int COUT, long tstr, long sstr, long wstr, long ystr,
                      const float* __restrict__ PARTp,
                      const float* __restrict__ bsumP,
                      unsigned short* __restrict__ Y0out) {
  constexpr int KS = CIN / 32;
  constexpr int ROWB = CIN * 2;
  constexpr int CPR = CIN / 8;
  constexpr bool BN0 = (SMODE >= 1 && SMODE <= 3);
  __shared__ __align__(16) unsigned char Xs[64 * ROWB];
  __shared__ float scs[BN0 ? CIN : 1];
  __shared__ float shs[BN0 ? CIN : 1];
  __shared__ float sc2[(SMODE == 3) ? CIN : 1];
  __shared__ float sh2[(SMODE == 3) ? CIN : 1];
  const int tid = threadIdx.x;
  const int lane = tid & 63, w = tid >> 6;
  const int g = lane >> 4, m = lane & 15;
  const int z = blockIdx.z;
  const int zi = z >> XDIV;
  const int obase = blockIdx.x * (OC << 6) + (w << 4);
  const int nbase = blockIdx.y << 6;
  const unsigned short* Tin = T0 + (size_t)zi * tstr;
  const unsigned short* Sin = (SMODE == 2 || SMODE == 3) ? (S0 + (size_t)zi * sstr) : nullptr;
  const unsigned short* Wb  = W0 + (size_t)z * wstr;
  unsigned short* Yout      = Yout0 + (size_t)z * ystr;
  float* outSums            = outSums0 + (size_t)z * SSTR;
  if (BN0) {
    const float* s0 = sums0A + (size_t)zi * s0str;
    const float* gg0; const float* bb0;
    SEL4(gg0, gb.g0, zi); SEL4(bb0, gb.b0, zi);
    const float invN = 1.f / 16384.f;
    for (int c = tid; c < CIN; c += 256) {
      float ss = 0.f, qq = 0.f;
#pragma unroll
      for (int p = 0; p < NCOPY; ++p) {
        ss += s0[p * 512 + c];
        qq += s0[p * 512 + 256 + c];
      }
      float mm = ss * invN;
      float vv = qq * invN - mm * mm;
      float s = gg0[c] * rsqrtf(vv + 1e-5f);
      scs[c] = s; shs[c] = bb0[c] - mm * s;
    }
    if (SMODE == 3) {
      const float* s1 = sums1A + (size_t)zi * s1str;
      const float* gg1; const float* bb1;
      SEL4(gg1, gb.g1, zi); SEL4(bb1, gb.b1, zi);
      for (int c = tid; c < CIN; c += 256) {
        float ss = 0.f, qq = 0.f;
#pragma unroll
        for (int p = 0; p < NCOPY; ++p) {
          ss += s1[p * 512 + c];
          qq += s1[p * 512 + 256 + c];
        }
        float mm = ss * invN;
        float vv = qq * invN - mm * mm;
        float s = gg1[c] * rsqrtf(vv + 1e-5f);
        sc2[c] = s; sh2[c] = bb1[c] - mm * s;
      }
    }
    __syncthreads();
  }
  if (SMODE == 4) {
    const int bb = nbase >> 10;
    const float invS = 1.f / bsumP[bb];
    const float* Pz = PARTp + (size_t)zi * ((size_t)2 << 20);
    unsigned short* Y0o = Y0out + (size_t)zi * ((size_t)2 << 20);
#pragma unroll
    for (int it = 0; it < (64 * CPR) / 256; ++it) {
      const int idx = it * 256 + tid;
      const int row = idx / CPR;
      const int cc = idx % CPR;
      bf16x8 v;
      if (cc < 8) {
        v = *reinterpret_cast<const bf16x8*>(
            Tin + ((size_t)(nbase + row) << 6) + cc * 8);
      } else {
        const float* p = Pz + ((size_t)(nbase + row) << 6) + ((cc - 8) << 3);
        float4 a0 = *reinterpret_cast<const float4*>(p);
        float4 a1 = *reinterpret_cast<const float4*>(p + 4);
        float4 b0 = *reinterpret_cast<const float4*>(p + ((size_t)1 << 20));
        float4 b1 = *reinterpret_cast<const float4*>(p + ((size_t)1 << 20) + 4);
        v[0] = (short)f2bf((a0.x + b0.x) * invS);
        v[1] = (short)f2bf((a0.y + b0.y) * invS);
        v[2] = (short)f2bf((a0.z + b0.z) * invS);
        v[3] = (short)f2bf((a0.w + b0.w) * invS);
        v[4] = (short)f2bf((a1.x + b1.x) * invS);
        v[5] = (short)f2bf((a1.y + b1.y) * invS);
        v[6] = (short)f2bf((a1.z + b1.z) * invS);
        v[7] = (short)f2bf((a1.w + b1.w) * invS);
      }
      *reinterpret_cast<bf16x8*>(Y0o + (size_t)(nbase + row) * 128 + cc * 8) = v;
      const int byte = (cc << 4) ^ ((row & 7) << 4);
      *reinterpret_cast<bf16x8*>(Xs + row * ROWB + byte) = v;
    }
  } else {
#pragma unroll
    for (int it = 0; it < (64 * CPR) / 256; ++it) {
      const int idx = it * 256 + tid;
      const int row = idx / CPR;
      const int cc = idx % CPR;
      bf16x8 v = *reinterpret_cast<const bf16x8*>(
          Tin + (size_t)(nbase + row) * CIN + cc * 8);
      if (BN0) {
        bf16x8 sv;
        if (SMODE >= 2)
          sv = *reinterpret_cast<const bf16x8*>(
              Sin + (size_t)(nbase + row) * CIN + cc * 8);
        const int c0 = cc * 8;
#pragma unroll
        for (int j = 0; j < 8; ++j) {
          float x = __uint_as_float((unsigned)(unsigned short)v[j] << 16);
          x = fmaf(x, scs[c0 + j], shs[c0 + j]);
          if (SMODE == 2)
            x += __uint_as_float((unsigned)(unsigned short)sv[j] << 16);
          if (SMODE == 3) {
            float y = __uint_as_float((unsigned)(unsigned short)sv[j] << 16);
            x += fmaf(y, sc2[c0 + j], sh2[c0 + j]);
          }
          x = fmaxf(x, 0.f);
          v[j] = (short)f2bf(x);
        }
      }
      const int byte = (cc << 4) ^ ((row & 7) << 4);
      *reinterpret_cast<bf16x8*>(Xs + row * ROWB + byte) = v;
    }
  }
  __syncthreads();
  bf16x8 af[KS][OC];
#pragma unroll
  for (int oc = 0; oc < OC; ++oc) {
    const unsigned short* Wr = Wb + (size_t)(obase + (oc << 6) + m) * CIN + (g << 3);
#pragma unroll
    for (int k = 0; k < KS; ++k)
      af[k][oc] = *reinterpret_cast<const bf16x8*>(Wr + (k << 5));
  }
  float sr[OC][4], qr[OC][4];
#pragma unroll
  for (int oc = 0; oc < OC; ++oc)
#pragma unroll
    for (int r = 0; r < 4; ++r) { sr[oc][r] = 0.f; qr[oc][r] = 0.f; }
#pragma unroll
  for (int nt = 0; nt < 4; ++nt) {
    const int row = (nt << 4) + m;
    const unsigned char* lrow = Xs + row * ROWB;
    const int swz = (row & 7) << 4;
    f32x4 acc[OC];
#pragma unroll
    for (int oc = 0; oc < OC; ++oc) acc[oc] = (f32x4){0.f, 0.f, 0.f, 0.f};
#pragma unroll
    for (int k = 0; k < KS; ++k) {
      const int byte = ((k << 6) + (g << 4)) ^ swz;
      bf16x8 bv = *reinterpret_cast<const bf16x8*>(lrow + byte);
#pragma unroll
      for (int oc = 0; oc < OC; ++oc)
        acc[oc] = __builtin_amdgcn_mfma_f32_16x16x32_bf16(af[k][oc], bv, acc[oc], 0, 0, 0);
    }
#pragma unroll
    for (int oc = 0; oc < OC; ++oc) {
      ushort4 v;
      v.x = f2bf(acc[oc][0]); v.y = f2bf(acc[oc][1]);
      v.z = f2bf(acc[oc][2]); v.w = f2bf(acc[oc][3]);
      *reinterpret_cast<ushort4*>(
          Yout + (size_t)(nbase + row) * COUT + obase + (oc << 6) + (g << 2)) = v;
#pragma unroll
      for (int r = 0; r < 4; ++r) {
        sr[oc][r] += acc[oc][r];
        qr[oc][r] = fmaf(acc[oc][r], acc[oc][r], qr[oc][r]);
      }
    }
  }
#pragma unroll
  for (int oc = 0; oc < OC; ++oc)
#pragma unroll
    for (int r = 0; r < 4; ++r) {
      for (int off = 1; off < 16; off <<= 1) {
        sr[oc][r] += __shfl_xor(sr[oc][r], off);
        qr[oc][r] += __shfl_xor(qr[oc][r], off);
      }
    }
  if (m == 0) {
    float* dst = outSums + (blockIdx.y & (NCOPY - 1)) * 512;
#pragma unroll
    for (int oc = 0; oc < OC; ++oc)
#pragma unroll
      for (int r = 0; r < 4; ++r) {
        atomicAdd(&dst[obase + (oc << 6) + (g << 2) + r], sr[oc][r]);
        atomicAdd(&dst[256 + obase + (oc << 6) + (g << 2) + r], qr[oc][r]);
      }
  }
}

// ---- writeout: fold conv6 stats inline, bn, LDS transpose, f32 out ---------
__global__ __launch_bounds__(256)
void writeout_t_kernel(const unsigned short* __restrict__ F0,
                       const float* __restrict__ sumsA,
                       GBArgs gb,
                       float* __restrict__ out0) {
  __shared__ float ts[64][66];
  __shared__ float sc[64], sh[64];
  const int tid = threadIdx.x;
  const int z = blockIdx.z;
  const size_t M1 = (size_t)1 << 20;
  const unsigned short* F = F0 + (size_t)z * M1;
  float* outp = out0 + (size_t)z * M1;
  if (tid < 64) {
    const float* sums = sumsA + (size_t)z * SSTR;
    const float* gg; const float* bb;
    SEL4(gg, gb.g0, z); SEL4(bb, gb.b0, z);
    float s0 = 0.f, q0 = 0.f;
#pragma unroll
    for (int p = 0; p < NCOPY; ++p) {
      s0 += sums[p * 512 + tid];
      q0 += sums[p * 512 + 256 + tid];
    }
    const float invN = 1.f / 16384.f;
    float mm = s0 * invN;
    float vv = q0 * invN - mm * mm;
    float s = gg[tid] * rsqrtf(vv + 1e-5f);
    sc[tid] = s; sh[tid] = bb[tid] - mm * s;
  }
  __syncthreads();
  const int n0 = blockIdx.x << 6;
  const int b = blockIdx.y;
  {
    const int n = tid >> 2, c0 = (tid & 3) << 4;
    const unsigned short* Fr = F + ((size_t)(b * 1024 + n0 + n) << 6) + c0;
    uint4 v0 = *reinterpret_cast<const uint4*>(Fr);
    uint4 v1 = *reinterpret_cast<const uint4*>(Fr + 8);
    unsigned vw[8] = {v0.x, v0.y, v0.z, v0.w, v1.x, v1.y, v1.z, v1.w};
#pragma unroll
    for (int jw = 0; jw < 8; ++jw) {
      int c = c0 + jw * 2;
      float x0 = __uint_as_float((vw[jw] & 0xffffu) << 16);
      float x1 = __uint_as_float((vw[jw] >> 16) << 16);
      ts[c][n] = fmaf(x0, sc[c], sh[c]);
      ts[c + 1][n] = fmaf(x1, sc[c + 1], sh[c + 1]);
    }
  }
  __syncthreads();
  const int c = tid >> 2, nq = (tid & 3) << 4;
  float* orow = outp + ((size_t)(b * 64 + c) << 10) + n0 + nq;
#pragma unroll
  for (int q = 0; q < 4; ++q) {
    float4 ov;
    ov.x = ts[c][nq + q * 4 + 0]; ov.y = ts[c][nq + q * 4 + 1];
    ov.z = ts[c][nq + q * 4 + 2]; ov.w = ts[c][nq + q * 4 + 3];
    *reinterpret_cast<float4*>(orow + q * 4) = ov;
  }
}

// ============================ host side =====================================
extern "C" void kernel_launch(void* const* d_in, const int* in_sizes, int n_in,
                              void* d_out, int out_size, void* d_ws, size_t ws_size,
                              hipStream_t stream) {
  float* wsf = (float*)d_ws;
  const size_t M1 = (size_t)1 << 20;
  const size_t H1 = (size_t)1 << 19;

  unsigned short* QAt = (unsigned short*)wsf;
  unsigned short* QBt = (unsigned short*)(wsf + H1);
  unsigned short* KAc = (unsigned short*)(wsf + 2 * H1);
  unsigned short* KBc = (unsigned short*)(wsf + 3 * H1);
  float* PART1 = wsf + 2 * M1;                             // [2M,6M): pv 2 + tpv 2
  unsigned short* XAt = (unsigned short*)(wsf + 6 * M1);   // [6M,7M)
  unsigned short* XBt = (unsigned short*)(wsf + 7 * M1);   // [7M,8M)
  unsigned short* Y0A = (unsigned short*)(wsf + 10 * M1);  // Y0A,Y0B @1M-float stride
  unsigned short* T1a = (unsigned short*)(wsf + 12 * M1);
  unsigned short* T2a = (unsigned short*)(wsf + 14 * M1);
  unsigned short* T3a = (unsigned short*)(wsf + 18 * M1);  // T3a,T5a,T3b,T5b @2M-float stride
  unsigned short* T4a = (unsigned short*)(wsf + 26 * M1);  // T4a,T4b @2M-float stride
  unsigned short* Fba = (unsigned short*)(wsf + 30 * M1);  // Fba,Fbb @0.5M-float stride
  float* tail = wsf + 31 * M1;
  float* bsum = tail;
  float* stats = tail + 16;
  unsigned short* wbf = (unsigned short*)(stats + 12 * SSTR);

  const float* pp[46];
  for (int i = 0; i < 46 && i < n_in; ++i) pp[i] = (const float*)d_in[i];

  const int initN = 16 + 12 * SSTR;

  // weight order: wqa,wqb,wka,wkb, w11a,w11b,w12a,w12b, w21a,w2sa,w21b,w2sb,
  //               w22a,w22b, woa,wob
  const int widx[16] = {2, 4, 6, 8,
                        10, 16, 13, 19, 22, 28, 31, 37, 25, 34, 40, 43};
  WcvtArgs wa;
  int woff[16];
  {
    int run = 0;
    for (int i = 0; i < 16; ++i) {
      wa.p[i] = pp[widx[i]];
      wa.sz[i] = in_sizes[widx[i]];
      wa.off[i] = run; woff[i] = run;
      run += in_sizes[widx[i]];
    }
  }

  // fused prep: wcvt + init + xcvt
  prep_kernel<<<1153, 256, 0, stream>>>(wa, wbf, tail, initN,
                                        pp[0], pp[1], XAt, XBt);

  // qk via MFMA (Q row-major, K transposed)
  QBias qb;
  qb.p[0] = pp[3]; qb.p[1] = pp[5]; qb.p[2] = pp[7]; qb.p[3] = pp[9];
  qk_mfma_kernel<<<dim3(16, 64), 256, 0, stream>>>(
      XAt, XBt, wbf + woff[0], qb, QAt, QBt, KAc, KBc);

  attn_mfma_kernel<<<dim3(16, 2, 32), 256, 0, stream>>>(
      QAt, QBt, KAc, KBc, PART1, bsum);

  float* S_c1 = stats;               // conv1 (2 z)
  float* S_c2 = stats + 2 * SSTR;    // conv2 (2 z)
  float* S_q  = stats + 4 * SSTR;    // quad (4 z)
  float* S_c4 = stats + 8 * SSTR;    // conv4 (2 z)
  float* S_c6 = stats + 10 * SSTR;   // conv6 (2 z)

  const long SH1 = (long)2 * M1;     // 1M-float stride in shorts
  const long SH2 = (long)4 * M1;     // 2M-float stride in shorts
  GBArgs gbE = {};
  GBArgs gb;

  // conv1 (SMODE4 concat, OC=2): {XAt, PART/bsum} -> T1, also writes Y0
  conv_mfma_kernel<128, 2, 4, 0><<<dim3(1, 256, 2), 256, 0, stream>>>(
      XAt, nullptr, wbf + woff[4], T1a, nullptr, 0, nullptr, 0, gbE,
      S_c1, 128, SH1, 0, 16384, SH1,
      PART1, bsum, Y0A);

  // conv2 (SMODE1, OC=2): T1 -> T2
  gb = gbE;
  gb.g0[0] = pp[11]; gb.b0[0] = pp[12]; gb.g0[1] = pp[17]; gb.b0[1] = pp[18];
  conv_mfma_kernel<128, 2, 1, 0><<<dim3(1, 256, 2), 256, 0, stream>>>(
      T1a, nullptr, wbf + woff[6], T2a, S_c1, SSTR, nullptr, 0, gb,
      S_c2, 128, SH1, 0, 16384, SH1,
      nullptr, nullptr, nullptr);

  // quad (SMODE2, OC=2): relu(bn(T2)+Y0) -> {T3a,T5a,T3b,T5b}
  gb = gbE;
  gb.g0[0] = pp[14]; gb.b0[0] = pp[15]; gb.g0[1] = pp[20]; gb.b0[1] = pp[21];
  conv_mfma_kernel<128, 2, 2, 1><<<dim3(2, 256, 4), 256, 0, stream>>>(
      T2a, Y0A, wbf + woff[8], T3a, S_c2, SSTR, nullptr, 0, gb,
      S_q, 256, SH1, SH1, 32768, SH2,
      nullptr, nullptr, nullptr);

  // conv4 (SMODE1, OC=2): T3 -> T4
  gb = gbE;
  gb.g0[0] = pp[23]; gb.b0[0] = pp[24]; gb.g0[1] = pp[32]; gb.b0[1] = pp[33];
  conv_mfma_kernel<256, 2, 1, 0><<<dim3(2, 256, 2), 256, 0, stream>>>(
      T3a, nullptr, wbf + woff[12], T4a, S_q, 2 * SSTR, nullptr, 0, gb,
      S_c4, 256, (long)8 * M1, 0, 65536, SH2,
      nullptr, nullptr, nullptr);

  // conv6 (SMODE3, OC=1): relu(bn(T4)+bn(T5)) -> Fb
  gb = gbE;
  gb.g0[0] = pp[26]; gb.b0[0] = pp[27]; gb.g0[1] = pp[35]; gb.b0[1] = pp[36];
  gb.g1[0] = pp[29]; gb.b1[0] = pp[30]; gb.g1[1] = pp[38]; gb.b1[1] = pp[39];
  conv_mfma_kernel<256, 1, 3, 0><<<dim3(1, 256, 2), 256, 0, stream>>>(
      T4a, T3a + SH2 /*T5a*/, wbf + woff[14], Fba, S_c4, SSTR,
      S_q + SSTR, 2 * SSTR, gb,
      S_c6, 64, SH2, (long)8 * M1, 16384, (long)M1,
      nullptr, nullptr, nullptr);

  // writeout (folds conv6 stats inline)
  gb = gbE;
  gb.g0[0] = pp[41]; gb.b0[0] = pp[42]; gb.g0[1] = pp[44]; gb.b0[1] = pp[45];
  writeout_t_kernel<<<dim3(16, BATCH, 2), 256, 0, stream>>>(
      Fba, S_c6, gb, (float*)d_out);
}

// Round 27
// 138.682 us; speedup vs baseline: 1.0307x; 1.0307x over previous
//
#include <hip/hip_runtime.h>
#include <hip/hip_bf16.h>
#include <cstddef>

static constexpr int BATCH = 16;
static constexpr int NCOPY = 16;
static constexpr int SSTR  = NCOPY * 512;   // floats per stat set

typedef __attribute__((ext_vector_type(8))) short bf16x8;
typedef __attribute__((ext_vector_type(4))) float f32x4;

__device__ __forceinline__ unsigned short f2bf(float f) {
  unsigned u = __float_as_uint(f);
  return (unsigned short)((u + 0x7fffu + ((u >> 16) & 1u)) >> 16);  // RNE
}

// pack two f32 -> bf16x2 in one v_perm_b32 (round-half-up via +0x8000)
__device__ __forceinline__ unsigned pack_bf2(float lo, float hi) {
  return __builtin_amdgcn_perm(__float_as_uint(hi) + 0x8000u,
                               __float_as_uint(lo) + 0x8000u,
                               0x07060302u);
}

#define SEL4(dst, arr, idx)                                   \
  do {                                                        \
    if ((idx) == 0) dst = arr[0];                             \
    else if ((idx) == 1) dst = arr[1];                        \
    else if ((idx) == 2) dst = arr[2];                        \
    else dst = arr[3];                                        \
  } while (0)

// ---- fused prep: [0,256) wcvt 16 mats; [256,641) init zero; [641,1153) xcvt
struct WcvtArgs { const float* p[16]; int sz[16]; int off[16]; };
__global__ __launch_bounds__(256)
void prep_kernel(WcvtArgs a, unsigned short* __restrict__ wdst,
                 float* __restrict__ initp, int initN,
                 const float* __restrict__ XA, const float* __restrict__ XB,
                 unsigned short* __restrict__ XAt, unsigned short* __restrict__ XBt) {
  __shared__ float ts[64][66];
  const int bx = blockIdx.x;
  const int tid = threadIdx.x;
  if (bx < 256) {
    const int t = bx >> 4, sub = bx & 15;
    const float* src = a.p[t];
    unsigned short* d = wdst + a.off[t];
    const int sz = a.sz[t];
    for (int i = sub * 256 + tid; i < sz; i += 4096)
      d[i] = f2bf(src[i]);
  } else if (bx < 641) {
    int idx = (bx - 256) * 256 + tid;
    if (idx < initN) initp[idx] = 0.f;
  } else {
    const int bx2 = bx - 641;
    const int z = bx2 >> 8;
    const int rem = bx2 & 255;
    const int b = rem >> 4;
    const int n0 = (rem & 15) << 6;
    const float* X = z ? XB : XA;
    unsigned short* XT = z ? XBt : XAt;
#pragma unroll
    for (int it = 0; it < 4; ++it) {
      int idx = it * 256 + tid;
      int c = idx >> 4, nq = (idx & 15) << 2;
      float4 v = *reinterpret_cast<const float4*>(X + ((size_t)(b * 64 + c) << 10) + n0 + nq);
      ts[c][nq] = v.x; ts[c][nq + 1] = v.y; ts[c][nq + 2] = v.z; ts[c][nq + 3] = v.w;
    }
    __syncthreads();
    const int n = tid >> 2, c0 = (tid & 3) << 4;
    unsigned short* dst = XT + ((size_t)(b * 1024 + n0 + n) << 6) + c0;
    unsigned w0 = (unsigned)f2bf(ts[c0 + 0][n]) | ((unsigned)f2bf(ts[c0 + 1][n]) << 16);
    unsigned w1 = (unsigned)f2bf(ts[c0 + 2][n]) | ((unsigned)f2bf(ts[c0 + 3][n]) << 16);
    unsigned w2 = (unsigned)f2bf(ts[c0 + 4][n]) | ((unsigned)f2bf(ts[c0 + 5][n]) << 16);
    unsigned w3 = (unsigned)f2bf(ts[c0 + 6][n]) | ((unsigned)f2bf(ts[c0 + 7][n]) << 16);
    unsigned w4 = (unsigned)f2bf(ts[c0 + 8][n]) | ((unsigned)f2bf(ts[c0 + 9][n]) << 16);
    unsigned w5 = (unsigned)f2bf(ts[c0 + 10][n]) | ((unsigned)f2bf(ts[c0 + 11][n]) << 16);
    unsigned w6 = (unsigned)f2bf(ts[c0 + 12][n]) | ((unsigned)f2bf(ts[c0 + 13][n]) << 16);
    unsigned w7 = (unsigned)f2bf(ts[c0 + 14][n]) | ((unsigned)f2bf(ts[c0 + 15][n]) << 16);
    *reinterpret_cast<uint4*>(dst) = make_uint4(w0, w1, w2, w3);
    *reinterpret_cast<uint4*>(dst + 8) = make_uint4(w4, w5, w6, w7);
  }
}

// ---- qk via MFMA: 4 projections; Q -> [b][n][64], K -> [b][c][n] -----------
struct QBias { const float* p[4]; };
__global__ __launch_bounds__(256, 4)
void qk_mfma_kernel(const unsigned short* __restrict__ XAt,
                    const unsigned short* __restrict__ XBt,
                    const unsigned short* __restrict__ wq,
                    QBias qb,
                    unsigned short* __restrict__ QAt, unsigned short* __restrict__ QBt,
                    unsigned short* __restrict__ KAc, unsigned short* __restrict__ KBc) {
  __shared__ __align__(16) unsigned char Xs[64 * 128];
  const int tid = threadIdx.x;
  const int lane = tid & 63, w = tid >> 6;
  const int g = lane >> 4, m = lane & 15;
  const int nbase = blockIdx.x << 6;
  const int z = blockIdx.y;
  const int which = z >> 4;
  const int b = z & 15;
  const unsigned short* XT = (which & 1) ? XBt : XAt;
  const unsigned short* Wb = wq + which * 4096;
  const float* bias;
  SEL4(bias, qb.p, which);
#pragma unroll
  for (int it = 0; it < 2; ++it) {
    int idx = it * 256 + tid;
    int row = idx >> 3, cc = idx & 7;
    bf16x8 v = *reinterpret_cast<const bf16x8*>(
        XT + ((size_t)(b * 1024 + nbase + row) << 6) + cc * 8);
    const int byte = (cc << 4) ^ ((row & 7) << 4);
    *reinterpret_cast<bf16x8*>(Xs + row * 128 + byte) = v;
  }
  __syncthreads();
  const int o0 = w << 4;
  const unsigned short* Wr = Wb + (size_t)(o0 + m) * 64 + (g << 3);
  bf16x8 af0 = *reinterpret_cast<const bf16x8*>(Wr);
  bf16x8 af1 = *reinterpret_cast<const bf16x8*>(Wr + 32);
  float bv[4];
#pragma unroll
  for (int r = 0; r < 4; ++r) bv[r] = bias[o0 + (g << 2) + r];
#pragma unroll
  for (int nt = 0; nt < 4; ++nt) {
    const int row = (nt << 4) + m;
    const unsigned char* lrow = Xs + row * 128;
    const int swz = (row & 7) << 4;
    f32x4 acc = (f32x4){0.f, 0.f, 0.f, 0.f};
    {
      bf16x8 b0 = *reinterpret_cast<const bf16x8*>(lrow + ((g << 4) ^ swz));
      acc = __builtin_amdgcn_mfma_f32_16x16x32_bf16(af0, b0, acc, 0, 0, 0);
      bf16x8 b1 = *reinterpret_cast<const bf16x8*>(lrow + ((64 + (g << 4)) ^ swz));
      acc = __builtin_amdgcn_mfma_f32_16x16x32_bf16(af1, b1, acc, 0, 0, 0);
    }
#pragma unroll
    for (int r = 0; r < 4; ++r) acc[r] += bv[r];
    if (which < 2) {
      unsigned short* Yq = (which == 0) ? QAt : QBt;
      ushort4 v;
      v.x = f2bf(acc[0]); v.y = f2bf(acc[1]);
      v.z = f2bf(acc[2]); v.w = f2bf(acc[3]);
      *reinterpret_cast<ushort4*>(
          Yq + ((size_t)(b * 1024 + nbase + row) << 6) + o0 + (g << 2)) = v;
    } else {
      unsigned short* Kc = (which == 2) ? KAc : KBc;
#pragma unroll
      for (int r = 0; r < 4; ++r)
        Kc[((size_t)b << 16) + ((size_t)(o0 + (g << 2) + r) << 10) + nbase + row] =
            f2bf(acc[r]);
    }
  }
}

// ---- combined MFMA attention: z<16 -> PV (batch z), z>=16 -> PtV (z-16) ----
// Fixed Q-tile in registers; per-jt tile staged in LDS (coalesced); P in LDS.
__global__ __launch_bounds__(256)
void attn_mfma_kernel(const unsigned short* __restrict__ QAt,
                      const unsigned short* __restrict__ QBt,
                      const unsigned short* __restrict__ KAc,
                      const unsigned short* __restrict__ KBc,
                      float* __restrict__ PART, float* __restrict__ bsum) {
  __shared__ __align__(16) unsigned short Vb[4096];
  __shared__ __align__(16) unsigned short Pl[4096];
  __shared__ float red[256];
  const int tid = threadIdx.x;
  const int lane = tid & 63, w = tid >> 6;
  const int g = lane >> 4, m = lane & 15;
  const int z = blockIdx.z;
  const bool isPV = (z < 16);
  const int b = z & 15;
  const size_t nb = (size_t)b << 16;
  const size_t M1 = (size_t)1 << 20;

  if (isPV) {
    const int i0 = blockIdx.x << 6;
    const int jbase = blockIdx.y << 9;
    // fixed QA tile fragments in registers (B operand rows irow=(n<<4)|m)
    bf16x8 ua0[4], ua1[4];
#pragma unroll
    for (int n = 0; n < 4; ++n) {
      const int irow = (n << 4) | m;
      const unsigned short* p = QAt + nb + ((size_t)(i0 + irow) << 6) + (g << 3);
      ua0[n] = *reinterpret_cast<const bf16x8*>(p);
      ua1[n] = *reinterpret_cast<const bf16x8*>(p + 32);
    }
    f32x4 accO[4];
#pragma unroll
    for (int n = 0; n < 4; ++n) accO[n] = (f32x4){0.f, 0.f, 0.f, 0.f};
    float psum = 0.f;
    for (int jt = 0; jt < 8; ++jt) {
      const int j0 = jbase + (jt << 6);
      __syncthreads();
      {
        const unsigned short* src = QBt + nb + ((size_t)j0 << 6);
#pragma unroll
        for (int s = 0; s < 2; ++s) {
          int idx = tid + (s << 8);
          int n = idx >> 3, cc = idx & 7;
          bf16x8 v = *reinterpret_cast<const bf16x8*>(src + (n << 6) + ((cc ^ (n & 7)) << 3));
          *reinterpret_cast<bf16x8*>(Vb + (idx << 3)) = v;
        }
      }
      __syncthreads();
      const int jrow = (w << 4) | m;
      bf16x8 a0 = *reinterpret_cast<const bf16x8*>(Vb + (jrow << 6) + ((g ^ (jrow & 7)) << 3));
      bf16x8 a1 = *reinterpret_cast<const bf16x8*>(Vb + (jrow << 6) + (((g + 4) ^ (jrow & 7)) << 3));
      f32x4 e[4];
#pragma unroll
      for (int n = 0; n < 4; ++n) {
        e[n] = (f32x4){0.f, 0.f, 0.f, 0.f};
        e[n] = __builtin_amdgcn_mfma_f32_16x16x32_bf16(a0, ua0[n], e[n], 0, 0, 0);
        e[n] = __builtin_amdgcn_mfma_f32_16x16x32_bf16(a1, ua1[n], e[n], 0, 0, 0);
      }
      const int j = (w << 4) | (g << 2);
#pragma unroll
      for (int n = 0; n < 4; ++n) {
        const int irow = (n << 4) | m;
        float p0 = __expf(-e[n][0]), p1 = __expf(-e[n][1]);
        float p2 = __expf(-e[n][2]), p3 = __expf(-e[n][3]);
        psum += (p0 + p1) + (p2 + p3);
        unsigned pk01 = pack_bf2(p0, p1);
        unsigned pk23 = pack_bf2(p2, p3);
        int base = irow << 6;
        int off0 = base + ((((j) >> 3) ^ (irow & 7)) << 3) + (j & 7);
        int off2 = base + ((((j + 2) >> 3) ^ (irow & 7)) << 3) + ((j + 2) & 7);
        *reinterpret_cast<unsigned*>(Pl + off0) = pk01;
        *reinterpret_cast<unsigned*>(Pl + off2) = pk23;
      }
      const int crow = (w << 4) | m;
      const unsigned short* kbp = KBc + nb + ((size_t)crow << 10) + j0 + (g << 3);
      bf16x8 ka0 = *reinterpret_cast<const bf16x8*>(kbp);
      bf16x8 ka1 = *reinterpret_cast<const bf16x8*>(kbp + 32);
      __syncthreads();
#pragma unroll
      for (int n = 0; n < 4; ++n) {
        const int irow = (n << 4) | m;
        bf16x8 p0 = *reinterpret_cast<const bf16x8*>(Pl + (irow << 6) + ((g ^ (irow & 7)) << 3));
        bf16x8 p1 = *reinterpret_cast<const bf16x8*>(Pl + (irow << 6) + (((g + 4) ^ (irow & 7)) << 3));
        accO[n] = __builtin_amdgcn_mfma_f32_16x16x32_bf16(ka0, p0, accO[n], 0, 0, 0);
        accO[n] = __builtin_amdgcn_mfma_f32_16x16x32_bf16(ka1, p1, accO[n], 0, 0, 0);
      }
    }
    float* OUT = PART + ((size_t)blockIdx.y * M1) + nb;
#pragma unroll
    for (int n = 0; n < 4; ++n) {
      const int ig = i0 + (n << 4) + m;
      const int c = (w << 4) + (g << 2);
      float4 o;
      o.x = accO[n][0]; o.y = accO[n][1]; o.z = accO[n][2]; o.w = accO[n][3];
      *reinterpret_cast<float4*>(OUT + ((size_t)ig << 6) + c) = o;
    }
    red[tid] = psum; __syncthreads();
    for (int s = 128; s > 0; s >>= 1) {
      if (tid < s) red[tid] += red[tid + s];
      __syncthreads();
    }
    if (tid == 0) atomicAdd(bsum + b, red[0]);
  } else {
    const int j0 = blockIdx.x << 6;
    const int ibase = blockIdx.y << 9;
    // fixed QB tile fragments in registers (B operand rows jrow=(n<<4)|m)
    bf16x8 ub0[4], ub1[4];
#pragma unroll
    for (int n = 0; n < 4; ++n) {
      const int jrow = (n << 4) | m;
      const unsigned short* p = QBt + nb + ((size_t)(j0 + jrow) << 6) + (g << 3);
      ub0[n] = *reinterpret_cast<const bf16x8*>(p);
      ub1[n] = *reinterpret_cast<const bf16x8*>(p + 32);
    }
    f32x4 accO[4];
#pragma unroll
    for (int n = 0; n < 4; ++n) accO[n] = (f32x4){0.f, 0.f, 0.f, 0.f};
    for (int it = 0; it < 8; ++it) {
      const int i0 = ibase + (it << 6);
      __syncthreads();
      {
        const unsigned short* src = QAt + nb + ((size_t)i0 << 6);
#pragma unroll
        for (int s = 0; s < 2; ++s) {
          int idx = tid + (s << 8);
          int n = idx >> 3, cc = idx & 7;
          bf16x8 v = *reinterpret_cast<const bf16x8*>(src + (n << 6) + ((cc ^ (n & 7)) << 3));
          *reinterpret_cast<bf16x8*>(Vb + (idx << 3)) = v;
        }
      }
      __syncthreads();
      const int irow_a = (w << 4) | m;
      bf16x8 a0 = *reinterpret_cast<const bf16x8*>(Vb + (irow_a << 6) + ((g ^ (irow_a & 7)) << 3));
      bf16x8 a1 = *reinterpret_cast<const bf16x8*>(Vb + (irow_a << 6) + (((g + 4) ^ (irow_a & 7)) << 3));
      f32x4 e[4];
#pragma unroll
      for (int n = 0; n < 4; ++n) {
        e[n] = (f32x4){0.f, 0.f, 0.f, 0.f};
        e[n] = __builtin_amdgcn_mfma_f32_16x16x32_bf16(a0, ub0[n], e[n], 0, 0, 0);
        e[n] = __builtin_amdgcn_mfma_f32_16x16x32_bf16(a1, ub1[n], e[n], 0, 0, 0);
      }
      const int i = (w << 4) | (g << 2);
#pragma unroll
      for (int n = 0; n < 4; ++n) {
        const int jrow = (n << 4) | m;
        float p0 = __expf(-e[n][0]), p1 = __expf(-e[n][1]);
        float p2 = __expf(-e[n][2]), p3 = __expf(-e[n][3]);
        unsigned pk01 = pack_bf2(p0, p1);
        unsigned pk23 = pack_bf2(p2, p3);
        int base = jrow << 6;
        int off0 = base + ((((i) >> 3) ^ (jrow & 7)) << 3) + (i & 7);
        int off2 = base + ((((i + 2) >> 3) ^ (jrow & 7)) << 3) + ((i + 2) & 7);
        *reinterpret_cast<unsigned*>(Pl + off0) = pk01;
        *reinterpret_cast<unsigned*>(Pl + off2) = pk23;
      }
      const int crow = (w << 4) | m;
      const unsigned short* kap = KAc + nb + ((size_t)crow << 10) + i0 + (g << 3);
      bf16x8 ka0 = *reinterpret_cast<const bf16x8*>(kap);
      bf16x8 ka1 = *reinterpret_cast<const bf16x8*>(kap + 32);
      __syncthreads();
#pragma unroll
      for (int n = 0; n < 4; ++n) {
        const int jrow = (n << 4) | m;
        bf16x8 p0 = *reinterpret_cast<const bf16x8*>(Pl + (jrow << 6) + ((g ^ (jrow & 7)) << 3));
        bf16x8 p1 = *reinterpret_cast<const bf16x8*>(Pl + (jrow << 6) + (((g + 4) ^ (jrow & 7)) << 3));
        accO[n] = __builtin_amdgcn_mfma_f32_16x16x32_bf16(ka0, p0, accO[n], 0, 0, 0);
        accO[n] = __builtin_amdgcn_mfma_f32_16x16x32_bf16(ka1, p1, accO[n], 0, 0, 0);
      }
    }
    float* OUT = PART + 2 * M1 + ((size_t)blockIdx.y * M1) + nb;
#pragma unroll
    for (int n = 0; n < 4; ++n) {
      const int jg = j0 + (n << 4) + m;
      const int c = (w << 4) + (g << 2);
      float4 o;
      o.x = accO[n][0]; o.y = accO[n][1]; o.z = accO[n][2]; o.w = accO[n][3];
      *reinterpret_cast<float4*>(OUT + ((size_t)jg << 6) + c) = o;
    }
  }
}

// ---- gamma/beta pointer sets (per z, uniform SEL4) -------------------------
struct GBArgs { const float* g0[4]; const float* b0[4];
                const float* g1[4]; const float* b1[4]; };

// ---- MFMA conv v13: LDS-staged tile, OC output groups per wave -------------
// SMODE: 0 plain; 1 relu(bn0(T)); 2 relu(bn0(T)+S); 3 relu(bn0(T)+bn1(S));
//        4 concat(XAt low, (PART0+PART1)/bsum high) + Y0 global store
template<int CIN, int OC, int SMODE, int XDIV>
__global__ __launch_bounds__(256, 4)
void conv_mfma_kernel(const unsigned short* __restrict__ T0,
                      const unsigned short* __restrict__ S0,
                      const unsigned short* __restrict__ W0,
                      unsigned short* __restrict__ Yout0,
                      const float* __restrict__ sums0A, long s0str,
                      const float* __restrict__ sums1A, long s1str,
                      GBArgs gb,
                      float* __restrict__ outSums0,
                      int COUT, long tstr, long sstr, long wstr, long ystr,
                      const float* __restrict__ PARTp,
                      const float* __restrict__ bsumP,
                      unsigned short* __restrict__ Y0out) {
  constexpr int KS = CIN / 32;
  constexpr int ROWB = CIN * 2;
  constexpr int CPR = CIN / 8;
  constexpr bool BN0 = (SMODE >= 1 && SMODE <= 3);
  __shared__ __align__(16) unsigned char Xs[64 * ROWB];
  __shared__ float scs[BN0 ? CIN : 1];
  __shared__ float shs[BN0 ? CIN : 1];
  __shared__ float sc2[(SMODE == 3) ? CIN : 1];
  __shared__ float sh2[(SMODE == 3) ? CIN : 1];
  const int tid = threadIdx.x;
  const int lane = tid & 63, w = tid >> 6;
  const int g = lane >> 4, m = lane & 15;
  const int z = blockIdx.z;
  const int zi = z >> XDIV;
  const int obase = blockIdx.x * (OC << 6) + (w << 4);
  const int nbase = blockIdx.y << 6;
  const unsigned short* Tin = T0 + (size_t)zi * tstr;
  const unsigned short* Sin = (SMODE == 2 || SMODE == 3) ? (S0 + (size_t)zi * sstr) : nullptr;
  const unsigned short* Wb  = W0 + (size_t)z * wstr;
  unsigned short* Yout      = Yout0 + (size_t)z * ystr;
  float* outSums            = outSums0 + (size_t)z * SSTR;
  if (BN0) {
    const float* s0 = sums0A + (size_t)zi * s0str;
    const float* gg0; const float* bb0;
    SEL4(gg0, gb.g0, zi); SEL4(bb0, gb.b0, zi);
    const float invN = 1.f / 16384.f;
    for (int c = tid; c < CIN; c += 256) {
      float ss = 0.f, qq = 0.f;
#pragma unroll
      for (int p = 0; p < NCOPY; ++p) {
        ss += s0[p * 512 + c];
        qq += s0[p * 512 + 256 + c];
      }
      float mm = ss * invN;
      float vv = qq * invN - mm * mm;
      float s = gg0[c] * rsqrtf(vv + 1e-5f);
      scs[c] = s; shs[c] = bb0[c] - mm * s;
    }
    if (SMODE == 3) {
      const float* s1 = sums1A + (size_t)zi * s1str;
      const float* gg1; const float* bb1;
      SEL4(gg1, gb.g1, zi); SEL4(bb1, gb.b1, zi);
      for (int c = tid; c < CIN; c += 256) {
        float ss = 0.f, qq = 0.f;
#pragma unroll
        for (int p = 0; p < NCOPY; ++p) {
          ss += s1[p * 512 + c];
          qq += s1[p * 512 + 256 + c];
        }
        float mm = ss * invN;
        float vv = qq * invN - mm * mm;
        float s = gg1[c] * rsqrtf(vv + 1e-5f);
        sc2[c] = s; sh2[c] = bb1[c] - mm * s;
      }
    }
    __syncthreads();
  }
  if (SMODE == 4) {
    const int bb = nbase >> 10;
    const float invS = 1.f / bsumP[bb];
    const float* Pz = PARTp + (size_t)zi * ((size_t)2 << 20);
    unsigned short* Y0o = Y0out + (size_t)zi * ((size_t)2 << 20);
#pragma unroll
    for (int it = 0; it < (64 * CPR) / 256; ++it) {
      const int idx = it * 256 + tid;
      const int row = idx / CPR;
      const int cc = idx % CPR;
      bf16x8 v;
      if (cc < 8) {
        v = *reinterpret_cast<const bf16x8*>(
            Tin + ((size_t)(nbase + row) << 6) + cc * 8);
      } else {
        const float* p = Pz + ((size_t)(nbase + row) << 6) + ((cc - 8) << 3);
        float4 a0 = *reinterpret_cast<const float4*>(p);
        float4 a1 = *reinterpret_cast<const float4*>(p + 4);
        float4 b0 = *reinterpret_cast<const float4*>(p + ((size_t)1 << 20));
        float4 b1 = *reinterpret_cast<const float4*>(p + ((size_t)1 << 20) + 4);
        v[0] = (short)f2bf((a0.x + b0.x) * invS);
        v[1] = (short)f2bf((a0.y + b0.y) * invS);
        v[2] = (short)f2bf((a0.z + b0.z) * invS);
        v[3] = (short)f2bf((a0.w + b0.w) * invS);
        v[4] = (short)f2bf((a1.x + b1.x) * invS);
        v[5] = (short)f2bf((a1.y + b1.y) * invS);
        v[6] = (short)f2bf((a1.z + b1.z) * invS);
        v[7] = (short)f2bf((a1.w + b1.w) * invS);
      }
      *reinterpret_cast<bf16x8*>(Y0o + (size_t)(nbase + row) * 128 + cc * 8) = v;
      const int byte = (cc << 4) ^ ((row & 7) << 4);
      *reinterpret_cast<bf16x8*>(Xs + row * ROWB + byte) = v;
    }
  } else {
#pragma unroll
    for (int it = 0; it < (64 * CPR) / 256; ++it) {
      const int idx = it * 256 + tid;
      const int row = idx / CPR;
      const int cc = idx % CPR;
      bf16x8 v = *reinterpret_cast<const bf16x8*>(
          Tin + (size_t)(nbase + row) * CIN + cc * 8);
      if (BN0) {
        bf16x8 sv;
        if (SMODE >= 2)
          sv = *reinterpret_cast<const bf16x8*>(
              Sin + (size_t)(nbase + row) * CIN + cc * 8);
        const int c0 = cc * 8;
#pragma unroll
        for (int j = 0; j < 8; ++j) {
          float x = __uint_as_float((unsigned)(unsigned short)v[j] << 16);
          x = fmaf(x, scs[c0 + j], shs[c0 + j]);
          if (SMODE == 2)
            x += __uint_as_float((unsigned)(unsigned short)sv[j] << 16);
          if (SMODE == 3) {
            float y = __uint_as_float((unsigned)(unsigned short)sv[j] << 16);
            x += fmaf(y, sc2[c0 + j], sh2[c0 + j]);
          }
          x = fmaxf(x, 0.f);
          v[j] = (short)f2bf(x);
        }
      }
      const int byte = (cc << 4) ^ ((row & 7) << 4);
      *reinterpret_cast<bf16x8*>(Xs + row * ROWB + byte) = v;
    }
  }
  __syncthreads();
  bf16x8 af[KS][OC];
#pragma unroll
  for (int oc = 0; oc < OC; ++oc) {
    const unsigned short* Wr = Wb + (size_t)(obase + (oc << 6) + m) * CIN + (g << 3);
#pragma unroll
    for (int k = 0; k < KS; ++k)
      af[k][oc] = *reinterpret_cast<const bf16x8*>(Wr + (k << 5));
  }
  float sr[OC][4], qr[OC][4];
#pragma unroll
  for (int oc = 0; oc < OC; ++oc)
#pragma unroll
    for (int r = 0; r < 4; ++r) { sr[oc][r] = 0.f; qr[oc][r] = 0.f; }
#pragma unroll
  for (int nt = 0; nt < 4; ++nt) {
    const int row = (nt << 4) + m;
    const unsigned char* lrow = Xs + row * ROWB;
    const int swz = (row & 7) << 4;
    f32x4 acc[OC];
#pragma unroll
    for (int oc = 0; oc < OC; ++oc) acc[oc] = (f32x4){0.f, 0.f, 0.f, 0.f};
#pragma unroll
    for (int k = 0; k < KS; ++k) {
      const int byte = ((k << 6) + (g << 4)) ^ swz;
      bf16x8 bv = *reinterpret_cast<const bf16x8*>(lrow + byte);
#pragma unroll
      for (int oc = 0; oc < OC; ++oc)
        acc[oc] = __builtin_amdgcn_mfma_f32_16x16x32_bf16(af[k][oc], bv, acc[oc], 0, 0, 0);
    }
#pragma unroll
    for (int oc = 0; oc < OC; ++oc) {
      ushort4 v;
      v.x = f2bf(acc[oc][0]); v.y = f2bf(acc[oc][1]);
      v.z = f2bf(acc[oc][2]); v.w = f2bf(acc[oc][3]);
      *reinterpret_cast<ushort4*>(
          Yout + (size_t)(nbase + row) * COUT + obase + (oc << 6) + (g << 2)) = v;
#pragma unroll
      for (int r = 0; r < 4; ++r) {
        sr[oc][r] += acc[oc][r];
        qr[oc][r] = fmaf(acc[oc][r], acc[oc][r], qr[oc][r]);
      }
    }
  }
#pragma unroll
  for (int oc = 0; oc < OC; ++oc)
#pragma unroll
    for (int r = 0; r < 4; ++r) {
      for (int off = 1; off < 16; off <<= 1) {
        sr[oc][r] += __shfl_xor(sr[oc][r], off);
        qr[oc][r] += __shfl_xor(qr[oc][r], off);
      }
    }
  if (m == 0) {
    float* dst = outSums + (blockIdx.y & (NCOPY - 1)) * 512;
#pragma unroll
    for (int oc = 0; oc < OC; ++oc)
#pragma unroll
      for (int r = 0; r < 4; ++r) {
        atomicAdd(&dst[obase + (oc << 6) + (g << 2) + r], sr[oc][r]);
        atomicAdd(&dst[256 + obase + (oc << 6) + (g << 2) + r], qr[oc][r]);
      }
  }
}

// ---- writeout: fold conv6 stats inline, bn, LDS transpose, f32 out ---------
__global__ __launch_bounds__(256)
void writeout_t_kernel(const unsigned short* __restrict__ F0,
                       const float* __restrict__ sumsA,
                       GBArgs gb,
                       float* __restrict__ out0) {
  __shared__ float ts[64][66];
  __shared__ float sc[64], sh[64];
  const int tid = threadIdx.x;
  const int z = blockIdx.z;
  const size_t M1 = (size_t)1 << 20;
  const unsigned short* F = F0 + (size_t)z * M1;
  float* outp = out0 + (size_t)z * M1;
  if (tid < 64) {
    const float* sums = sumsA + (size_t)z * SSTR;
    const float* gg; const float* bb;
    SEL4(gg, gb.g0, z); SEL4(bb, gb.b0, z);
    float s0 = 0.f, q0 = 0.f;
#pragma unroll
    for (int p = 0; p < NCOPY; ++p) {
      s0 += sums[p * 512 + tid];
      q0 += sums[p * 512 + 256 + tid];
    }
    const float invN = 1.f / 16384.f;
    float mm = s0 * invN;
    float vv = q0 * invN - mm * mm;
    float s = gg[tid] * rsqrtf(vv + 1e-5f);
    sc[tid] = s; sh[tid] = bb[tid] - mm * s;
  }
  __syncthreads();
  const int n0 = blockIdx.x << 6;
  const int b = blockIdx.y;
  {
    const int n = tid >> 2, c0 = (tid & 3) << 4;
    const unsigned short* Fr = F + ((size_t)(b * 1024 + n0 + n) << 6) + c0;
    uint4 v0 = *reinterpret_cast<const uint4*>(Fr);
    uint4 v1 = *reinterpret_cast<const uint4*>(Fr + 8);
    unsigned vw[8] = {v0.x, v0.y, v0.z, v0.w, v1.x, v1.y, v1.z, v1.w};
#pragma unroll
    for (int jw = 0; jw < 8; ++jw) {
      int c = c0 + jw * 2;
      float x0 = __uint_as_float((vw[jw] & 0xffffu) << 16);
      float x1 = __uint_as_float((vw[jw] >> 16) << 16);
      ts[c][n] = fmaf(x0, sc[c], sh[c]);
      ts[c + 1][n] = fmaf(x1, sc[c + 1], sh[c + 1]);
    }
  }
  __syncthreads();
  const int c = tid >> 2, nq = (tid & 3) << 4;
  float* orow = outp + ((size_t)(b * 64 + c) << 10) + n0 + nq;
#pragma unroll
  for (int q = 0; q < 4; ++q) {
    float4 ov;
    ov.x = ts[c][nq + q * 4 + 0]; ov.y = ts[c][nq + q * 4 + 1];
    ov.z = ts[c][nq + q * 4 + 2]; ov.w = ts[c][nq + q * 4 + 3];
    *reinterpret_cast<float4*>(orow + q * 4) = ov;
  }
}

// ============================ host side =====================================
extern "C" void kernel_launch(void* const* d_in, const int* in_sizes, int n_in,
                              void* d_out, int out_size, void* d_ws, size_t ws_size,
                              hipStream_t stream) {
  float* wsf = (float*)d_ws;
  const size_t M1 = (size_t)1 << 20;
  const size_t H1 = (size_t)1 << 19;

  unsigned short* QAt = (unsigned short*)wsf;
  unsigned short* QBt = (unsigned short*)(wsf + H1);
  unsigned short* KAc = (unsigned short*)(wsf + 2 * H1);
  unsigned short* KBc = (unsigned short*)(wsf + 3 * H1);
  float* PART1 = wsf + 2 * M1;                             // [2M,6M): pv 2 + tpv 2
  unsigned short* XAt = (unsigned short*)(wsf + 6 * M1);   // [6M,7M)
  unsigned short* XBt = (unsigned short*)(wsf + 7 * M1);   // [7M,8M)
  unsigned short* Y0A = (unsigned short*)(wsf + 10 * M1);  // Y0A,Y0B @1M-float stride
  unsigned short* T1a = (unsigned short*)(wsf + 12 * M1);
  unsigned short* T2a = (unsigned short*)(wsf + 14 * M1);
  unsigned short* T3a = (unsigned short*)(wsf + 18 * M1);  // T3a,T5a,T3b,T5b @2M-float stride
  unsigned short* T4a = (unsigned short*)(wsf + 26 * M1);  // T4a,T4b @2M-float stride
  unsigned short* Fba = (unsigned short*)(wsf + 30 * M1);  // Fba,Fbb @0.5M-float stride
  float* tail = wsf + 31 * M1;
  float* bsum = tail;
  float* stats = tail + 16;
  unsigned short* wbf = (unsigned short*)(stats + 12 * SSTR);

  const float* pp[46];
  for (int i = 0; i < 46 && i < n_in; ++i) pp[i] = (const float*)d_in[i];

  const int initN = 16 + 12 * SSTR;

  // weight order: wqa,wqb,wka,wkb, w11a,w11b,w12a,w12b, w21a,w2sa,w21b,w2sb,
  //               w22a,w22b, woa,wob
  const int widx[16] = {2, 4, 6, 8,
                        10, 16, 13, 19, 22, 28, 31, 37, 25, 34, 40, 43};
  WcvtArgs wa;
  int woff[16];
  {
    int run = 0;
    for (int i = 0; i < 16; ++i) {
      wa.p[i] = pp[widx[i]];
      wa.sz[i] = in_sizes[widx[i]];
      wa.off[i] = run; woff[i] = run;
      run += in_sizes[widx[i]];
    }
  }

  // fused prep: wcvt + init + xcvt
  prep_kernel<<<1153, 256, 0, stream>>>(wa, wbf, tail, initN,
                                        pp[0], pp[1], XAt, XBt);

  // qk via MFMA (Q row-major, K transposed)
  QBias qb;
  qb.p[0] = pp[3]; qb.p[1] = pp[5]; qb.p[2] = pp[7]; qb.p[3] = pp[9];
  qk_mfma_kernel<<<dim3(16, 64), 256, 0, stream>>>(
      XAt, XBt, wbf + woff[0], qb, QAt, QBt, KAc, KBc);

  attn_mfma_kernel<<<dim3(16, 2, 32), 256, 0, stream>>>(
      QAt, QBt, KAc, KBc, PART1, bsum);

  float* S_c1 = stats;               // conv1 (2 z)
  float* S_c2 = stats + 2 * SSTR;    // conv2 (2 z)
  float* S_q  = stats + 4 * SSTR;    // quad (4 z)
  float* S_c4 = stats + 8 * SSTR;    // conv4 (2 z)
  float* S_c6 = stats + 10 * SSTR;   // conv6 (2 z)

  const long SH1 = (long)2 * M1;     // 1M-float stride in shorts
  const long SH2 = (long)4 * M1;     // 2M-float stride in shorts
  GBArgs gbE = {};
  GBArgs gb;

  // conv1 (SMODE4 concat, OC=2): {XAt, PART/bsum} -> T1, also writes Y0
  conv_mfma_kernel<128, 2, 4, 0><<<dim3(1, 256, 2), 256, 0, stream>>>(
      XAt, nullptr, wbf + woff[4], T1a, nullptr, 0, nullptr, 0, gbE,
      S_c1, 128, SH1, 0, 16384, SH1,
      PART1, bsum, Y0A);

  // conv2 (SMODE1, OC=2): T1 -> T2
  gb = gbE;
  gb.g0[0] = pp[11]; gb.b0[0] = pp[12]; gb.g0[1] = pp[17]; gb.b0[1] = pp[18];
  conv_mfma_kernel<128, 2, 1, 0><<<dim3(1, 256, 2), 256, 0, stream>>>(
      T1a, nullptr, wbf + woff[6], T2a, S_c1, SSTR, nullptr, 0, gb,
      S_c2, 128, SH1, 0, 16384, SH1,
      nullptr, nullptr, nullptr);

  // quad (SMODE2, OC=2): relu(bn(T2)+Y0) -> {T3a,T5a,T3b,T5b}
  gb = gbE;
  gb.g0[0] = pp[14]; gb.b0[0] = pp[15]; gb.g0[1] = pp[20]; gb.b0[1] = pp[21];
  conv_mfma_kernel<128, 2, 2, 1><<<dim3(2, 256, 4), 256, 0, stream>>>(
      T2a, Y0A, wbf + woff[8], T3a, S_c2, SSTR, nullptr, 0, gb,
      S_q, 256, SH1, SH1, 32768, SH2,
      nullptr, nullptr, nullptr);

  // conv4 (SMODE1, OC=2): T3 -> T4
  gb = gbE;
  gb.g0[0] = pp[23]; gb.b0[0] = pp[24]; gb.g0[1] = pp[32]; gb.b0[1] = pp[33];
  conv_mfma_kernel<256, 2, 1, 0><<<dim3(2, 256, 2), 256, 0, stream>>>(
      T3a, nullptr, wbf + woff[12], T4a, S_q, 2 * SSTR, nullptr, 0, gb,
      S_c4, 256, (long)8 * M1, 0, 65536, SH2,
      nullptr, nullptr, nullptr);

  // conv6 (SMODE3, OC=1): relu(bn(T4)+bn(T5)) -> Fb
  gb = gbE;
  gb.g0[0] = pp[26]; gb.b0[0] = pp[27]; gb.g0[1] = pp[35]; gb.b0[1] = pp[36];
  gb.g1[0] = pp[29]; gb.b1[0] = pp[30]; gb.g1[1] = pp[38]; gb.b1[1] = pp[39];
  conv_mfma_kernel<256, 1, 3, 0><<<dim3(1, 256, 2), 256, 0, stream>>>(
      T4a, T3a + SH2 /*T5a*/, wbf + woff[14], Fba, S_c4, SSTR,
      S_q + SSTR, 2 * SSTR, gb,
      S_c6, 64, SH2, (long)8 * M1, 16384, (long)M1,
      nullptr, nullptr, nullptr);

  // writeout (folds conv6 stats inline)
  gb = gbE;
  gb.g0[0] = pp[41]; gb.b0[0] = pp[42]; gb.g0[1] = pp[44]; gb.b0[1] = pp[45];
  writeout_t_kernel<<<dim3(16, BATCH, 2), 256, 0, stream>>>(
      Fba, S_c6, gb, (float*)d_out);
}

// Round 28
// 135.928 us; speedup vs baseline: 1.0516x; 1.0203x over previous
//
#include <hip/hip_runtime.h>
#include <hip/hip_bf16.h>
#include <cstddef>

static constexpr int BATCH = 16;
static constexpr int NCOPY = 16;
static constexpr int SSTR  = NCOPY * 512;   // floats per stat set

typedef __attribute__((ext_vector_type(8))) short bf16x8;
typedef __attribute__((ext_vector_type(4))) float f32x4;

__device__ __forceinline__ unsigned short f2bf(float f) {
  unsigned u = __float_as_uint(f);
  return (unsigned short)((u + 0x7fffu + ((u >> 16) & 1u)) >> 16);  // RNE
}

// pack two f32 -> bf16x2 in one v_perm_b32 (round-half-up via +0x8000)
__device__ __forceinline__ unsigned pack_bf2(float lo, float hi) {
  return __builtin_amdgcn_perm(__float_as_uint(hi) + 0x8000u,
                               __float_as_uint(lo) + 0x8000u,
                               0x07060302u);
}

#define SEL4(dst, arr, idx)                                   \
  do {                                                        \
    if ((idx) == 0) dst = arr[0];                             \
    else if ((idx) == 1) dst = arr[1];                        \
    else if ((idx) == 2) dst = arr[2];                        \
    else dst = arr[3];                                        \
  } while (0)

// ---- fused prep: [0,256) wcvt 16 mats; [256,641) init zero; [641,1153) xcvt
struct WcvtArgs { const float* p[16]; int sz[16]; int off[16]; };
__global__ __launch_bounds__(256)
void prep_kernel(WcvtArgs a, unsigned short* __restrict__ wdst,
                 float* __restrict__ initp, int initN,
                 const float* __restrict__ XA, const float* __restrict__ XB,
                 unsigned short* __restrict__ XAt, unsigned short* __restrict__ XBt) {
  __shared__ float ts[64][66];
  const int bx = blockIdx.x;
  const int tid = threadIdx.x;
  if (bx < 256) {
    const int t = bx >> 4, sub = bx & 15;
    const float* src = a.p[t];
    unsigned short* d = wdst + a.off[t];
    const int sz = a.sz[t];
    for (int i = sub * 256 + tid; i < sz; i += 4096)
      d[i] = f2bf(src[i]);
  } else if (bx < 641) {
    int idx = (bx - 256) * 256 + tid;
    if (idx < initN) initp[idx] = 0.f;
  } else {
    const int bx2 = bx - 641;
    const int z = bx2 >> 8;
    const int rem = bx2 & 255;
    const int b = rem >> 4;
    const int n0 = (rem & 15) << 6;
    const float* X = z ? XB : XA;
    unsigned short* XT = z ? XBt : XAt;
#pragma unroll
    for (int it = 0; it < 4; ++it) {
      int idx = it * 256 + tid;
      int c = idx >> 4, nq = (idx & 15) << 2;
      float4 v = *reinterpret_cast<const float4*>(X + ((size_t)(b * 64 + c) << 10) + n0 + nq);
      ts[c][nq] = v.x; ts[c][nq + 1] = v.y; ts[c][nq + 2] = v.z; ts[c][nq + 3] = v.w;
    }
    __syncthreads();
    const int n = tid >> 2, c0 = (tid & 3) << 4;
    unsigned short* dst = XT + ((size_t)(b * 1024 + n0 + n) << 6) + c0;
    unsigned w0 = (unsigned)f2bf(ts[c0 + 0][n]) | ((unsigned)f2bf(ts[c0 + 1][n]) << 16);
    unsigned w1 = (unsigned)f2bf(ts[c0 + 2][n]) | ((unsigned)f2bf(ts[c0 + 3][n]) << 16);
    unsigned w2 = (unsigned)f2bf(ts[c0 + 4][n]) | ((unsigned)f2bf(ts[c0 + 5][n]) << 16);
    unsigned w3 = (unsigned)f2bf(ts[c0 + 6][n]) | ((unsigned)f2bf(ts[c0 + 7][n]) << 16);
    unsigned w4 = (unsigned)f2bf(ts[c0 + 8][n]) | ((unsigned)f2bf(ts[c0 + 9][n]) << 16);
    unsigned w5 = (unsigned)f2bf(ts[c0 + 10][n]) | ((unsigned)f2bf(ts[c0 + 11][n]) << 16);
    unsigned w6 = (unsigned)f2bf(ts[c0 + 12][n]) | ((unsigned)f2bf(ts[c0 + 13][n]) << 16);
    unsigned w7 = (unsigned)f2bf(ts[c0 + 14][n]) | ((unsigned)f2bf(ts[c0 + 15][n]) << 16);
    *reinterpret_cast<uint4*>(dst) = make_uint4(w0, w1, w2, w3);
    *reinterpret_cast<uint4*>(dst + 8) = make_uint4(w4, w5, w6, w7);
  }
}

// ---- qk via MFMA: 4 projections; Q -> [b][n][64], K -> [b][c][n] -----------
struct QBias { const float* p[4]; };
__global__ __launch_bounds__(256, 4)
void qk_mfma_kernel(const unsigned short* __restrict__ XAt,
                    const unsigned short* __restrict__ XBt,
                    const unsigned short* __restrict__ wq,
                    QBias qb,
                    unsigned short* __restrict__ QAt, unsigned short* __restrict__ QBt,
                    unsigned short* __restrict__ KAc, unsigned short* __restrict__ KBc) {
  __shared__ __align__(16) unsigned char Xs[64 * 128];
  const int tid = threadIdx.x;
  const int lane = tid & 63, w = tid >> 6;
  const int g = lane >> 4, m = lane & 15;
  const int nbase = blockIdx.x << 6;
  const int z = blockIdx.y;
  const int which = z >> 4;
  const int b = z & 15;
  const unsigned short* XT = (which & 1) ? XBt : XAt;
  const unsigned short* Wb = wq + which * 4096;
  const float* bias;
  SEL4(bias, qb.p, which);
#pragma unroll
  for (int it = 0; it < 2; ++it) {
    int idx = it * 256 + tid;
    int row = idx >> 3, cc = idx & 7;
    bf16x8 v = *reinterpret_cast<const bf16x8*>(
        XT + ((size_t)(b * 1024 + nbase + row) << 6) + cc * 8);
    const int byte = (cc << 4) ^ ((row & 7) << 4);
    *reinterpret_cast<bf16x8*>(Xs + row * 128 + byte) = v;
  }
  __syncthreads();
  const int o0 = w << 4;
  const unsigned short* Wr = Wb + (size_t)(o0 + m) * 64 + (g << 3);
  bf16x8 af0 = *reinterpret_cast<const bf16x8*>(Wr);
  bf16x8 af1 = *reinterpret_cast<const bf16x8*>(Wr + 32);
  float bv[4];
#pragma unroll
  for (int r = 0; r < 4; ++r) bv[r] = bias[o0 + (g << 2) + r];
#pragma unroll
  for (int nt = 0; nt < 4; ++nt) {
    const int row = (nt << 4) + m;
    const unsigned char* lrow = Xs + row * 128;
    const int swz = (row & 7) << 4;
    f32x4 acc = (f32x4){0.f, 0.f, 0.f, 0.f};
    {
      bf16x8 b0 = *reinterpret_cast<const bf16x8*>(lrow + ((g << 4) ^ swz));
      acc = __builtin_amdgcn_mfma_f32_16x16x32_bf16(af0, b0, acc, 0, 0, 0);
      bf16x8 b1 = *reinterpret_cast<const bf16x8*>(lrow + ((64 + (g << 4)) ^ swz));
      acc = __builtin_amdgcn_mfma_f32_16x16x32_bf16(af1, b1, acc, 0, 0, 0);
    }
#pragma unroll
    for (int r = 0; r < 4; ++r) acc[r] += bv[r];
    if (which < 2) {
      unsigned short* Yq = (which == 0) ? QAt : QBt;
      ushort4 v;
      v.x = f2bf(acc[0]); v.y = f2bf(acc[1]);
      v.z = f2bf(acc[2]); v.w = f2bf(acc[3]);
      *reinterpret_cast<ushort4*>(
          Yq + ((size_t)(b * 1024 + nbase + row) << 6) + o0 + (g << 2)) = v;
    } else {
      unsigned short* Kc = (which == 2) ? KAc : KBc;
#pragma unroll
      for (int r = 0; r < 4; ++r)
        Kc[((size_t)b << 16) + ((size_t)(o0 + (g << 2) + r) << 10) + nbase + row] =
            f2bf(acc[r]);
    }
  }
}

// ---- combined MFMA attention: z<16 -> PV (batch z), z>=16 -> PtV (z-16) ----
// PART layout [b][i][64] f32 per chunk (PV chunks at 0,1M; PtV at 2M,3M).
__global__ __launch_bounds__(256)
void attn_mfma_kernel(const unsigned short* __restrict__ QAt,
                      const unsigned short* __restrict__ QBt,
                      const unsigned short* __restrict__ KAc,
                      const unsigned short* __restrict__ KBc,
                      float* __restrict__ PART, float* __restrict__ bsum) {
  __shared__ __align__(16) unsigned short Ua[4096];
  __shared__ __align__(16) unsigned short Vb[4096];
  __shared__ __align__(16) unsigned short Pl[4096];
  __shared__ float red[256];
  const int tid = threadIdx.x;
  const int lane = tid & 63, w = tid >> 6;
  const int g = lane >> 4, m = lane & 15;
  const int z = blockIdx.z;
  const bool isPV = (z < 16);
  const int b = z & 15;
  const size_t nb = (size_t)b << 16;
  const size_t M1 = (size_t)1 << 20;

  if (isPV) {
    const int i0 = blockIdx.x << 6;
    const int jbase = blockIdx.y << 9;
    {
      const unsigned short* src = QAt + nb + ((size_t)i0 << 6);
#pragma unroll
      for (int s = 0; s < 2; ++s) {
        int idx = tid + (s << 8);
        int n = idx >> 3, cc = idx & 7;
        bf16x8 v = *reinterpret_cast<const bf16x8*>(src + (n << 6) + ((cc ^ (n & 7)) << 3));
        *reinterpret_cast<bf16x8*>(Ua + (idx << 3)) = v;
      }
    }
    f32x4 accO[4];
#pragma unroll
    for (int n = 0; n < 4; ++n) accO[n] = (f32x4){0.f, 0.f, 0.f, 0.f};
    float psum = 0.f;
    for (int jt = 0; jt < 8; ++jt) {
      const int j0 = jbase + (jt << 6);
      __syncthreads();
      {
        const unsigned short* src = QBt + nb + ((size_t)j0 << 6);
#pragma unroll
        for (int s = 0; s < 2; ++s) {
          int idx = tid + (s << 8);
          int n = idx >> 3, cc = idx & 7;
          bf16x8 v = *reinterpret_cast<const bf16x8*>(src + (n << 6) + ((cc ^ (n & 7)) << 3));
          *reinterpret_cast<bf16x8*>(Vb + (idx << 3)) = v;
        }
      }
      __syncthreads();
      const int jrow = (w << 4) | m;
      bf16x8 a0 = *reinterpret_cast<const bf16x8*>(Vb + (jrow << 6) + ((g ^ (jrow & 7)) << 3));
      bf16x8 a1 = *reinterpret_cast<const bf16x8*>(Vb + (jrow << 6) + (((g + 4) ^ (jrow & 7)) << 3));
      f32x4 e[4];
#pragma unroll
      for (int n = 0; n < 4; ++n) {
        const int irow = (n << 4) | m;
        bf16x8 b0v = *reinterpret_cast<const bf16x8*>(Ua + (irow << 6) + ((g ^ (irow & 7)) << 3));
        bf16x8 b1v = *reinterpret_cast<const bf16x8*>(Ua + (irow << 6) + (((g + 4) ^ (irow & 7)) << 3));
        e[n] = (f32x4){0.f, 0.f, 0.f, 0.f};
        e[n] = __builtin_amdgcn_mfma_f32_16x16x32_bf16(a0, b0v, e[n], 0, 0, 0);
        e[n] = __builtin_amdgcn_mfma_f32_16x16x32_bf16(a1, b1v, e[n], 0, 0, 0);
      }
      const int j = (w << 4) | (g << 2);
#pragma unroll
      for (int n = 0; n < 4; ++n) {
        const int irow = (n << 4) | m;
        float p0 = __expf(-e[n][0]), p1 = __expf(-e[n][1]);
        float p2 = __expf(-e[n][2]), p3 = __expf(-e[n][3]);
        psum += (p0 + p1) + (p2 + p3);
        unsigned pk01 = pack_bf2(p0, p1);
        unsigned pk23 = pack_bf2(p2, p3);
        int base = irow << 6;
        int off0 = base + ((((j) >> 3) ^ (irow & 7)) << 3) + (j & 7);
        int off2 = base + ((((j + 2) >> 3) ^ (irow & 7)) << 3) + ((j + 2) & 7);
        *reinterpret_cast<unsigned*>(Pl + off0) = pk01;
        *reinterpret_cast<unsigned*>(Pl + off2) = pk23;
      }
      const int crow = (w << 4) | m;
      const unsigned short* kbp = KBc + nb + ((size_t)crow << 10) + j0 + (g << 3);
      bf16x8 ka0 = *reinterpret_cast<const bf16x8*>(kbp);
      bf16x8 ka1 = *reinterpret_cast<const bf16x8*>(kbp + 32);
      __syncthreads();
#pragma unroll
      for (int n = 0; n < 4; ++n) {
        const int irow = (n << 4) | m;
        bf16x8 p0 = *reinterpret_cast<const bf16x8*>(Pl + (irow << 6) + ((g ^ (irow & 7)) << 3));
        bf16x8 p1 = *reinterpret_cast<const bf16x8*>(Pl + (irow << 6) + (((g + 4) ^ (irow & 7)) << 3));
        accO[n] = __builtin_amdgcn_mfma_f32_16x16x32_bf16(ka0, p0, accO[n], 0, 0, 0);
        accO[n] = __builtin_amdgcn_mfma_f32_16x16x32_bf16(ka1, p1, accO[n], 0, 0, 0);
      }
    }
    float* OUT = PART + ((size_t)blockIdx.y * M1) + nb;
#pragma unroll
    for (int n = 0; n < 4; ++n) {
      const int ig = i0 + (n << 4) + m;
      const int c = (w << 4) + (g << 2);
      float4 o;
      o.x = accO[n][0]; o.y = accO[n][1]; o.z = accO[n][2]; o.w = accO[n][3];
      *reinterpret_cast<float4*>(OUT + ((size_t)ig << 6) + c) = o;
    }
    red[tid] = psum; __syncthreads();
    for (int s = 128; s > 0; s >>= 1) {
      if (tid < s) red[tid] += red[tid + s];
      __syncthreads();
    }
    if (tid == 0) atomicAdd(bsum + b, red[0]);
  } else {
    const int j0 = blockIdx.x << 6;
    const int ibase = blockIdx.y << 9;
    {
      const unsigned short* src = QBt + nb + ((size_t)j0 << 6);
#pragma unroll
      for (int s = 0; s < 2; ++s) {
        int idx = tid + (s << 8);
        int n = idx >> 3, cc = idx & 7;
        bf16x8 v = *reinterpret_cast<const bf16x8*>(src + (n << 6) + ((cc ^ (n & 7)) << 3));
        *reinterpret_cast<bf16x8*>(Ua + (idx << 3)) = v;
      }
    }
    f32x4 accO[4];
#pragma unroll
    for (int n = 0; n < 4; ++n) accO[n] = (f32x4){0.f, 0.f, 0.f, 0.f};
    for (int it = 0; it < 8; ++it) {
      const int i0 = ibase + (it << 6);
      __syncthreads();
      {
        const unsigned short* src = QAt + nb + ((size_t)i0 << 6);
#pragma unroll
        for (int s = 0; s < 2; ++s) {
          int idx = tid + (s << 8);
          int n = idx >> 3, cc = idx & 7;
          bf16x8 v = *reinterpret_cast<const bf16x8*>(src + (n << 6) + ((cc ^ (n & 7)) << 3));
          *reinterpret_cast<bf16x8*>(Vb + (idx << 3)) = v;
        }
      }
      __syncthreads();
      const int irow_a = (w << 4) | m;
      bf16x8 a0 = *reinterpret_cast<const bf16x8*>(Vb + (irow_a << 6) + ((g ^ (irow_a & 7)) << 3));
      bf16x8 a1 = *reinterpret_cast<const bf16x8*>(Vb + (irow_a << 6) + (((g + 4) ^ (irow_a & 7)) << 3));
      f32x4 e[4];
#pragma unroll
      for (int n = 0; n < 4; ++n) {
        const int jrow = (n << 4) | m;
        bf16x8 b0v = *reinterpret_cast<const bf16x8*>(Ua + (jrow << 6) + ((g ^ (jrow & 7)) << 3));
        bf16x8 b1v = *reinterpret_cast<const bf16x8*>(Ua + (jrow << 6) + (((g + 4) ^ (jrow & 7)) << 3));
        e[n] = (f32x4){0.f, 0.f, 0.f, 0.f};
        e[n] = __builtin_amdgcn_mfma_f32_16x16x32_bf16(a0, b0v, e[n], 0, 0, 0);
        e[n] = __builtin_amdgcn_mfma_f32_16x16x32_bf16(a1, b1v, e[n], 0, 0, 0);
      }
      const int i = (w << 4) | (g << 2);
#pragma unroll
      for (int n = 0; n < 4; ++n) {
        const int jrow = (n << 4) | m;
        float p0 = __expf(-e[n][0]), p1 = __expf(-e[n][1]);
        float p2 = __expf(-e[n][2]), p3 = __expf(-e[n][3]);
        unsigned pk01 = pack_bf2(p0, p1);
        unsigned pk23 = pack_bf2(p2, p3);
        int base = jrow << 6;
        int off0 = base + ((((i) >> 3) ^ (jrow & 7)) << 3) + (i & 7);
        int off2 = base + ((((i + 2) >> 3) ^ (jrow & 7)) << 3) + ((i + 2) & 7);
        *reinterpret_cast<unsigned*>(Pl + off0) = pk01;
        *reinterpret_cast<unsigned*>(Pl + off2) = pk23;
      }
      const int crow = (w << 4) | m;
      const unsigned short* kap = KAc + nb + ((size_t)crow << 10) + i0 + (g << 3);
      bf16x8 ka0 = *reinterpret_cast<const bf16x8*>(kap);
      bf16x8 ka1 = *reinterpret_cast<const bf16x8*>(kap + 32);
      __syncthreads();
#pragma unroll
      for (int n = 0; n < 4; ++n) {
        const int jrow = (n << 4) | m;
        bf16x8 p0 = *reinterpret_cast<const bf16x8*>(Pl + (jrow << 6) + ((g ^ (jrow & 7)) << 3));
        bf16x8 p1 = *reinterpret_cast<const bf16x8*>(Pl + (jrow << 6) + (((g + 4) ^ (jrow & 7)) << 3));
        accO[n] = __builtin_amdgcn_mfma_f32_16x16x32_bf16(ka0, p0, accO[n], 0, 0, 0);
        accO[n] = __builtin_amdgcn_mfma_f32_16x16x32_bf16(ka1, p1, accO[n], 0, 0, 0);
      }
    }
    float* OUT = PART + 2 * M1 + ((size_t)blockIdx.y * M1) + nb;
#pragma unroll
    for (int n = 0; n < 4; ++n) {
      const int jg = j0 + (n << 4) + m;
      const int c = (w << 4) + (g << 2);
      float4 o;
      o.x = accO[n][0]; o.y = accO[n][1]; o.z = accO[n][2]; o.w = accO[n][3];
      *reinterpret_cast<float4*>(OUT + ((size_t)jg << 6) + c) = o;
    }
  }
}

// ---- gamma/beta pointer sets (per z, uniform SEL4) -------------------------
struct GBArgs { const float* g0[4]; const float* b0[4];
                const float* g1[4]; const float* b1[4]; };

// ---- MFMA conv v13: LDS-staged tile, OC output groups per wave -------------
// SMODE: 0 plain; 1 relu(bn0(T)); 2 relu(bn0(T)+S); 3 relu(bn0(T)+bn1(S));
//        4 concat(XAt low, (PART0+PART1)/bsum high) + Y0 global store
template<int CIN, int OC, int SMODE, int XDIV>
__global__ __launch_bounds__(256, 4)
void conv_mfma_kernel(const unsigned short* __restrict__ T0,
                      const unsigned short* __restrict__ S0,
                      const unsigned short* __restrict__ W0,
                      unsigned short* __restrict__ Yout0,
                      const float* __restrict__ sums0A, long s0str,
                      const float* __restrict__ sums1A, long s1str,
                      GBArgs gb,
                      float* __restrict__ outSums0,
                      int COUT, long tstr, long sstr, long wstr, long ystr,
                      const float* __restrict__ PARTp,
                      const float* __restrict__ bsumP,
                      unsigned short* __restrict__ Y0out) {
  constexpr int KS = CIN / 32;
  constexpr int ROWB = CIN * 2;
  constexpr int CPR = CIN / 8;
  constexpr bool BN0 = (SMODE >= 1 && SMODE <= 3);
  __shared__ __align__(16) unsigned char Xs[64 * ROWB];
  __shared__ float scs[BN0 ? CIN : 1];
  __shared__ float shs[BN0 ? CIN : 1];
  __shared__ float sc2[(SMODE == 3) ? CIN : 1];
  __shared__ float sh2[(SMODE == 3) ? CIN : 1];
  const int tid = threadIdx.x;
  const int lane = tid & 63, w = tid >> 6;
  const int g = lane >> 4, m = lane & 15;
  const int z = blockIdx.z;
  const int zi = z >> XDIV;
  const int obase = blockIdx.x * (OC << 6) + (w << 4);
  const int nbase = blockIdx.y << 6;
  const unsigned short* Tin = T0 + (size_t)zi * tstr;
  const unsigned short* Sin = (SMODE == 2 || SMODE == 3) ? (S0 + (size_t)zi * sstr) : nullptr;
  const unsigned short* Wb  = W0 + (size_t)z * wstr;
  unsigned short* Yout      = Yout0 + (size_t)z * ystr;
  float* outSums            = outSums0 + (size_t)z * SSTR;
  if (BN0) {
    const float* s0 = sums0A + (size_t)zi * s0str;
    const float* gg0; const float* bb0;
    SEL4(gg0, gb.g0, zi); SEL4(bb0, gb.b0, zi);
    const float invN = 1.f / 16384.f;
    for (int c = tid; c < CIN; c += 256) {
      float ss = 0.f, qq = 0.f;
#pragma unroll
      for (int p = 0; p < NCOPY; ++p) {
        ss += s0[p * 512 + c];
        qq += s0[p * 512 + 256 + c];
      }
      float mm = ss * invN;
      float vv = qq * invN - mm * mm;
      float s = gg0[c] * rsqrtf(vv + 1e-5f);
      scs[c] = s; shs[c] = bb0[c] - mm * s;
    }
    if (SMODE == 3) {
      const float* s1 = sums1A + (size_t)zi * s1str;
      const float* gg1; const float* bb1;
      SEL4(gg1, gb.g1, zi); SEL4(bb1, gb.b1, zi);
      for (int c = tid; c < CIN; c += 256) {
        float ss = 0.f, qq = 0.f;
#pragma unroll
        for (int p = 0; p < NCOPY; ++p) {
          ss += s1[p * 512 + c];
          qq += s1[p * 512 + 256 + c];
        }
        float mm = ss * invN;
        float vv = qq * invN - mm * mm;
        float s = gg1[c] * rsqrtf(vv + 1e-5f);
        sc2[c] = s; sh2[c] = bb1[c] - mm * s;
      }
    }
    __syncthreads();
  }
  if (SMODE == 4) {
    const int bb = nbase >> 10;
    const float invS = 1.f / bsumP[bb];
    const float* Pz = PARTp + (size_t)zi * ((size_t)2 << 20);
    unsigned short* Y0o = Y0out + (size_t)zi * ((size_t)2 << 20);
#pragma unroll
    for (int it = 0; it < (64 * CPR) / 256; ++it) {
      const int idx = it * 256 + tid;
      const int row = idx / CPR;
      const int cc = idx % CPR;
      bf16x8 v;
      if (cc < 8) {
        v = *reinterpret_cast<const bf16x8*>(
            Tin + ((size_t)(nbase + row) << 6) + cc * 8);
      } else {
        const float* p = Pz + ((size_t)(nbase + row) << 6) + ((cc - 8) << 3);
        float4 a0 = *reinterpret_cast<const float4*>(p);
        float4 a1 = *reinterpret_cast<const float4*>(p + 4);
        float4 b0 = *reinterpret_cast<const float4*>(p + ((size_t)1 << 20));
        float4 b1 = *reinterpret_cast<const float4*>(p + ((size_t)1 << 20) + 4);
        v[0] = (short)f2bf((a0.x + b0.x) * invS);
        v[1] = (short)f2bf((a0.y + b0.y) * invS);
        v[2] = (short)f2bf((a0.z + b0.z) * invS);
        v[3] = (short)f2bf((a0.w + b0.w) * invS);
        v[4] = (short)f2bf((a1.x + b1.x) * invS);
        v[5] = (short)f2bf((a1.y + b1.y) * invS);
        v[6] = (short)f2bf((a1.z + b1.z) * invS);
        v[7] = (short)f2bf((a1.w + b1.w) * invS);
      }
      *reinterpret_cast<bf16x8*>(Y0o + (size_t)(nbase + row) * 128 + cc * 8) = v;
      const int byte = (cc << 4) ^ ((row & 7) << 4);
      *reinterpret_cast<bf16x8*>(Xs + row * ROWB + byte) = v;
    }
  } else {
#pragma unroll
    for (int it = 0; it < (64 * CPR) / 256; ++it) {
      const int idx = it * 256 + tid;
      const int row = idx / CPR;
      const int cc = idx % CPR;
      bf16x8 v = *reinterpret_cast<const bf16x8*>(
          Tin + (size_t)(nbase + row) * CIN + cc * 8);
      if (BN0) {
        bf16x8 sv;
        if (SMODE >= 2)
          sv = *reinterpret_cast<const bf16x8*>(
              Sin + (size_t)(nbase + row) * CIN + cc * 8);
        const int c0 = cc * 8;
#pragma unroll
        for (int j = 0; j < 8; ++j) {
          float x = __uint_as_float((unsigned)(unsigned short)v[j] << 16);
          x = fmaf(x, scs[c0 + j], shs[c0 + j]);
          if (SMODE == 2)
            x += __uint_as_float((unsigned)(unsigned short)sv[j] << 16);
          if (SMODE == 3) {
            float y = __uint_as_float((unsigned)(unsigned short)sv[j] << 16);
            x += fmaf(y, sc2[c0 + j], sh2[c0 + j]);
          }
          x = fmaxf(x, 0.f);
          v[j] = (short)f2bf(x);
        }
      }
      const int byte = (cc << 4) ^ ((row & 7) << 4);
      *reinterpret_cast<bf16x8*>(Xs + row * ROWB + byte) = v;
    }
  }
  __syncthreads();
  bf16x8 af[KS][OC];
#pragma unroll
  for (int oc = 0; oc < OC; ++oc) {
    const unsigned short* Wr = Wb + (size_t)(obase + (oc << 6) + m) * CIN + (g << 3);
#pragma unroll
    for (int k = 0; k < KS; ++k)
      af[k][oc] = *reinterpret_cast<const bf16x8*>(Wr + (k << 5));
  }
  float sr[OC][4], qr[OC][4];
#pragma unroll
  for (int oc = 0; oc < OC; ++oc)
#pragma unroll
    for (int r = 0; r < 4; ++r) { sr[oc][r] = 0.f; qr[oc][r] = 0.f; }
#pragma unroll
  for (int nt = 0; nt < 4; ++nt) {
    const int row = (nt << 4) + m;
    const unsigned char* lrow = Xs + row * ROWB;
    const int swz = (row & 7) << 4;
    f32x4 acc[OC];
#pragma unroll
    for (int oc = 0; oc < OC; ++oc) acc[oc] = (f32x4){0.f, 0.f, 0.f, 0.f};
#pragma unroll
    for (int k = 0; k < KS; ++k) {
      const int byte = ((k << 6) + (g << 4)) ^ swz;
      bf16x8 bv = *reinterpret_cast<const bf16x8*>(lrow + byte);
#pragma unroll
      for (int oc = 0; oc < OC; ++oc)
        acc[oc] = __builtin_amdgcn_mfma_f32_16x16x32_bf16(af[k][oc], bv, acc[oc], 0, 0, 0);
    }
#pragma unroll
    for (int oc = 0; oc < OC; ++oc) {
      ushort4 v;
      v.x = f2bf(acc[oc][0]); v.y = f2bf(acc[oc][1]);
      v.z = f2bf(acc[oc][2]); v.w = f2bf(acc[oc][3]);
      *reinterpret_cast<ushort4*>(
          Yout + (size_t)(nbase + row) * COUT + obase + (oc << 6) + (g << 2)) = v;
#pragma unroll
      for (int r = 0; r < 4; ++r) {
        sr[oc][r] += acc[oc][r];
        qr[oc][r] = fmaf(acc[oc][r], acc[oc][r], qr[oc][r]);
      }
    }
  }
#pragma unroll
  for (int oc = 0; oc < OC; ++oc)
#pragma unroll
    for (int r = 0; r < 4; ++r) {
      for (int off = 1; off < 16; off <<= 1) {
        sr[oc][r] += __shfl_xor(sr[oc][r], off);
        qr[oc][r] += __shfl_xor(qr[oc][r], off);
      }
    }
  if (m == 0) {
    float* dst = outSums + (blockIdx.y & (NCOPY - 1)) * 512;
#pragma unroll
    for (int oc = 0; oc < OC; ++oc)
#pragma unroll
      for (int r = 0; r < 4; ++r) {
        atomicAdd(&dst[obase + (oc << 6) + (g << 2) + r], sr[oc][r]);
        atomicAdd(&dst[256 + obase + (oc << 6) + (g << 2) + r], qr[oc][r]);
      }
  }
}

// ---- writeout: fold conv6 stats inline, bn, LDS transpose, f32 out ---------
__global__ __launch_bounds__(256)
void writeout_t_kernel(const unsigned short* __restrict__ F0,
                       const float* __restrict__ sumsA,
                       GBArgs gb,
                       float* __restrict__ out0) {
  __shared__ float ts[64][66];
  __shared__ float sc[64], sh[64];
  const int tid = threadIdx.x;
  const int z = blockIdx.z;
  const size_t M1 = (size_t)1 << 20;
  const unsigned short* F = F0 + (size_t)z * M1;
  float* outp = out0 + (size_t)z * M1;
  if (tid < 64) {
    const float* sums = sumsA + (size_t)z * SSTR;
    const float* gg; const float* bb;
    SEL4(gg, gb.g0, z); SEL4(bb, gb.b0, z);
    float s0 = 0.f, q0 = 0.f;
#pragma unroll
    for (int p = 0; p < NCOPY; ++p) {
      s0 += sums[p * 512 + tid];
      q0 += sums[p * 512 + 256 + tid];
    }
    const float invN = 1.f / 16384.f;
    float mm = s0 * invN;
    float vv = q0 * invN - mm * mm;
    float s = gg[tid] * rsqrtf(vv + 1e-5f);
    sc[tid] = s; sh[tid] = bb[tid] - mm * s;
  }
  __syncthreads();
  const int n0 = blockIdx.x << 6;
  const int b = blockIdx.y;
  {
    const int n = tid >> 2, c0 = (tid & 3) << 4;
    const unsigned short* Fr = F + ((size_t)(b * 1024 + n0 + n) << 6) + c0;
    uint4 v0 = *reinterpret_cast<const uint4*>(Fr);
    uint4 v1 = *reinterpret_cast<const uint4*>(Fr + 8);
    unsigned vw[8] = {v0.x, v0.y, v0.z, v0.w, v1.x, v1.y, v1.z, v1.w};
#pragma unroll
    for (int jw = 0; jw < 8; ++jw) {
      int c = c0 + jw * 2;
      float x0 = __uint_as_float((vw[jw] & 0xffffu) << 16);
      float x1 = __uint_as_float((vw[jw] >> 16) << 16);
      ts[c][n] = fmaf(x0, sc[c], sh[c]);
      ts[c + 1][n] = fmaf(x1, sc[c + 1], sh[c + 1]);
    }
  }
  __syncthreads();
  const int c = tid >> 2, nq = (tid & 3) << 4;
  float* orow = outp + ((size_t)(b * 64 + c) << 10) + n0 + nq;
#pragma unroll
  for (int q = 0; q < 4; ++q) {
    float4 ov;
    ov.x = ts[c][nq + q * 4 + 0]; ov.y = ts[c][nq + q * 4 + 1];
    ov.z = ts[c][nq + q * 4 + 2]; ov.w = ts[c][nq + q * 4 + 3];
    *reinterpret_cast<float4*>(orow + q * 4) = ov;
  }
}

// ============================ host side =====================================
extern "C" void kernel_launch(void* const* d_in, const int* in_sizes, int n_in,
                              void* d_out, int out_size, void* d_ws, size_t ws_size,
                              hipStream_t stream) {
  float* wsf = (float*)d_ws;
  const size_t M1 = (size_t)1 << 20;
  const size_t H1 = (size_t)1 << 19;

  unsigned short* QAt = (unsigned short*)wsf;
  unsigned short* QBt = (unsigned short*)(wsf + H1);
  unsigned short* KAc = (unsigned short*)(wsf + 2 * H1);
  unsigned short* KBc = (unsigned short*)(wsf + 3 * H1);
  float* PART1 = wsf + 2 * M1;                             // [2M,6M): pv 2 + tpv 2
  unsigned short* XAt = (unsigned short*)(wsf + 6 * M1);   // [6M,7M)
  unsigned short* XBt = (unsigned short*)(wsf + 7 * M1);   // [7M,8M)
  unsigned short* Y0A = (unsigned short*)(wsf + 10 * M1);  // Y0A,Y0B @1M-float stride
  unsigned short* T1a = (unsigned short*)(wsf + 12 * M1);
  unsigned short* T2a = (unsigned short*)(wsf + 14 * M1);
  unsigned short* T3a = (unsigned short*)(wsf + 18 * M1);  // T3a,T5a,T3b,T5b @2M-float stride
  unsigned short* T4a = (unsigned short*)(wsf + 26 * M1);  // T4a,T4b @2M-float stride
  unsigned short* Fba = (unsigned short*)(wsf + 30 * M1);  // Fba,Fbb @0.5M-float stride
  float* tail = wsf + 31 * M1;
  float* bsum = tail;
  float* stats = tail + 16;
  unsigned short* wbf = (unsigned short*)(stats + 12 * SSTR);

  const float* pp[46];
  for (int i = 0; i < 46 && i < n_in; ++i) pp[i] = (const float*)d_in[i];

  const int initN = 16 + 12 * SSTR;

  // weight order: wqa,wqb,wka,wkb, w11a,w11b,w12a,w12b, w21a,w2sa,w21b,w2sb,
  //               w22a,w22b, woa,wob
  const int widx[16] = {2, 4, 6, 8,
                        10, 16, 13, 19, 22, 28, 31, 37, 25, 34, 40, 43};
  WcvtArgs wa;
  int woff[16];
  {
    int run = 0;
    for (int i = 0; i < 16; ++i) {
      wa.p[i] = pp[widx[i]];
      wa.sz[i] = in_sizes[widx[i]];
      wa.off[i] = run; woff[i] = run;
      run += in_sizes[widx[i]];
    }
  }

  // fused prep: wcvt + init + xcvt
  prep_kernel<<<1153, 256, 0, stream>>>(wa, wbf, tail, initN,
                                        pp[0], pp[1], XAt, XBt);

  // qk via MFMA (Q row-major, K transposed)
  QBias qb;
  qb.p[0] = pp[3]; qb.p[1] = pp[5]; qb.p[2] = pp[7]; qb.p[3] = pp[9];
  qk_mfma_kernel<<<dim3(16, 64), 256, 0, stream>>>(
      XAt, XBt, wbf + woff[0], qb, QAt, QBt, KAc, KBc);

  attn_mfma_kernel<<<dim3(16, 2, 32), 256, 0, stream>>>(
      QAt, QBt, KAc, KBc, PART1, bsum);

  float* S_c1 = stats;               // conv1 (2 z)
  float* S_c2 = stats + 2 * SSTR;    // conv2 (2 z)
  float* S_q  = stats + 4 * SSTR;    // quad (4 z)
  float* S_c4 = stats + 8 * SSTR;    // conv4 (2 z)
  float* S_c6 = stats + 10 * SSTR;   // conv6 (2 z)

  const long SH1 = (long)2 * M1;     // 1M-float stride in shorts
  const long SH2 = (long)4 * M1;     // 2M-float stride in shorts
  GBArgs gbE = {};
  GBArgs gb;

  // conv1 (SMODE4 concat, OC=2): {XAt, PART/bsum} -> T1, also writes Y0
  conv_mfma_kernel<128, 2, 4, 0><<<dim3(1, 256, 2), 256, 0, stream>>>(
      XAt, nullptr, wbf + woff[4], T1a, nullptr, 0, nullptr, 0, gbE,
      S_c1, 128, SH1, 0, 16384, SH1,
      PART1, bsum, Y0A);

  // conv2 (SMODE1, OC=2): T1 -> T2
  gb = gbE;
  gb.g0[0] = pp[11]; gb.b0[0] = pp[12]; gb.g0[1] = pp[17]; gb.b0[1] = pp[18];
  conv_mfma_kernel<128, 2, 1, 0><<<dim3(1, 256, 2), 256, 0, stream>>>(
      T1a, nullptr, wbf + woff[6], T2a, S_c1, SSTR, nullptr, 0, gb,
      S_c2, 128, SH1, 0, 16384, SH1,
      nullptr, nullptr, nullptr);

  // quad (SMODE2, OC=2): relu(bn(T2)+Y0) -> {T3a,T5a,T3b,T5b}
  gb = gbE;
  gb.g0[0] = pp[14]; gb.b0[0] = pp[15]; gb.g0[1] = pp[20]; gb.b0[1] = pp[21];
  conv_mfma_kernel<128, 2, 2, 1><<<dim3(2, 256, 4), 256, 0, stream>>>(
      T2a, Y0A, wbf + woff[8], T3a, S_c2, SSTR, nullptr, 0, gb,
      S_q, 256, SH1, SH1, 32768, SH2,
      nullptr, nullptr, nullptr);

  // conv4 (SMODE1, OC=2): T3 -> T4
  gb = gbE;
  gb.g0[0] = pp[23]; gb.b0[0] = pp[24]; gb.g0[1] = pp[32]; gb.b0[1] = pp[33];
  conv_mfma_kernel<256, 2, 1, 0><<<dim3(2, 256, 2), 256, 0, stream>>>(
      T3a, nullptr, wbf + woff[12], T4a, S_q, 2 * SSTR, nullptr, 0, gb,
      S_c4, 256, (long)8 * M1, 0, 65536, SH2,
      nullptr, nullptr, nullptr);

  // conv6 (SMODE3, OC=1): relu(bn(T4)+bn(T5)) -> Fb
  gb = gbE;
  gb.g0[0] = pp[26]; gb.b0[0] = pp[27]; gb.g0[1] = pp[35]; gb.b0[1] = pp[36];
  gb.g1[0] = pp[29]; gb.b1[0] = pp[30]; gb.g1[1] = pp[38]; gb.b1[1] = pp[39];
  conv_mfma_kernel<256, 1, 3, 0><<<dim3(1, 256, 2), 256, 0, stream>>>(
      T4a, T3a + SH2 /*T5a*/, wbf + woff[14], Fba, S_c4, SSTR,
      S_q + SSTR, 2 * SSTR, gb,
      S_c6, 64, SH2, (long)8 * M1, 16384, (long)M1,
      nullptr, nullptr, nullptr);

  // writeout (folds conv6 stats inline)
  gb = gbE;
  gb.g0[0] = pp[41]; gb.b0[0] = pp[42]; gb.g0[1] = pp[44]; gb.b0[1] = pp[45];
  writeout_t_kernel<<<dim3(16, BATCH, 2), 256, 0, stream>>>(
      Fba, S_c6, gb, (float*)d_out);
}